// Round 3
// baseline (6333.118 us; speedup 1.0000x reference)
//
#include <hip/hip_runtime.h>
#include <math.h>

#define TIN   128
#define TOUT  64
#define ND    128
#define HID   512
#define PROJD 256
#define BSZ   256
#define NWG   256

using f32x4 = __attribute__((ext_vector_type(4))) float;
using s16x8 = __attribute__((ext_vector_type(8))) short;
typedef unsigned short u16;

__device__ __forceinline__ u16 f2bf(float x) {
    unsigned int u = __builtin_bit_cast(unsigned int, x);
    u += 0x7fffu + ((u >> 16) & 1u);          // RNE (finite values)
    return (u16)(u >> 16);
}
__device__ __forceinline__ float bf2f(u16 b) {
    unsigned int u = ((unsigned int)b) << 16;
    return __builtin_bit_cast(float, u);
}
__device__ __forceinline__ f32x4 mfma16(s16x8 a, s16x8 b, f32x4 c) {
    return __builtin_amdgcn_mfma_f32_16x16x32_bf16(a, b, c, 0, 0, 0);
}
__device__ __forceinline__ f32x4 fz() { return (f32x4){0.f, 0.f, 0.f, 0.f}; }

// ================= prep kernels (parallel, off critical path) =================

// GRU weights: [jf16(32)][kb(20: 0-15 Wh,16-19 Wi)][g(3)][hl(2)][64][8]
__global__ __launch_bounds__(256)
void pack_gru_w(const float* __restrict__ Wh, const float* __restrict__ Wi,
                u16* __restrict__ dst)
{
    int idx  = blockIdx.x * 256 + threadIdx.x;       // 32*20*3*64 = 122880
    int lane = idx & 63;
    int t    = idx >> 6;
    int g    = t % 3;  t /= 3;
    int kb   = t % 20; t /= 20;
    int jf16 = t;
    if (jf16 >= 32) return;
    int row = g * HID + jf16 * 16 + (lane & 15);
    int kk  = kb * 32 + (lane >> 4) * 8;
    float v[8];
    if (kb < 16) { const float* s = Wh + (size_t)row * HID + kk;
        #pragma unroll
        for (int i = 0; i < 8; ++i) v[i] = s[i];
    } else { const float* s = Wi + (size_t)row * ND + (kk - HID);
        #pragma unroll
        for (int i = 0; i < 8; ++i) v[i] = s[i];
    }
    size_t base = ((((size_t)(jf16 * 20 + kb) * 3 + g) * 2) * 64 + lane) * 8;
    #pragma unroll
    for (int i = 0; i < 8; ++i) {
        u16 hi = f2bf(v[i]);
        dst[base + i]       = hi;
        dst[base + 512 + i] = f2bf(v[i] - bf2f(hi));
    }
}

// Wc = dec_Wi @ Wo  [1536][256] -> frags [jf16(32)][kb(8)][g(3)][hl][64][8]
__global__ __launch_bounds__(256)
void pack_wc(const float* __restrict__ Wi, const float* __restrict__ Wo,
             u16* __restrict__ dst)
{
    int idx  = blockIdx.x * 256 + threadIdx.x;       // 32*8*3*64 = 49152
    int lane = idx & 63;
    int t    = idx >> 6;
    int g    = t % 3; t /= 3;
    int kb   = t % 8; t /= 8;
    int jf16 = t;
    if (jf16 >= 32) return;
    int row = g * HID + jf16 * 16 + (lane & 15);
    int p0  = kb * 32 + (lane >> 4) * 8;
    float acc[8] = {0.f,0.f,0.f,0.f,0.f,0.f,0.f,0.f};
    for (int o = 0; o < ND; ++o) {
        float wi = Wi[(size_t)row * ND + o];
        const float* wo = Wo + (size_t)o * PROJD + p0;
        #pragma unroll
        for (int i = 0; i < 8; ++i) acc[i] += wi * wo[i];
    }
    size_t base = ((((size_t)(jf16 * 8 + kb) * 3 + g) * 2) * 64 + lane) * 8;
    #pragma unroll
    for (int i = 0; i < 8; ++i) {
        u16 hi = f2bf(acc[i]);
        dst[base + i]       = hi;
        dst[base + 512 + i] = f2bf(acc[i] - bf2f(hi));
    }
}

// plain weight (no gates): [jf16][kb][hl][64][8]
__global__ __launch_bounds__(256)
void pack_plain_w(const float* __restrict__ W, int K, int NF, int KB,
                  u16* __restrict__ dst)
{
    int idx  = blockIdx.x * 256 + threadIdx.x;
    int lane = idx & 63;
    int t    = idx >> 6;
    int kb   = t % KB;
    int jf16 = t / KB;
    if (jf16 >= NF) return;
    int row = jf16 * 16 + (lane & 15);
    int kk  = kb * 32 + (lane >> 4) * 8;
    const float* s = W + (size_t)row * K + kk;
    size_t base = (((size_t)(jf16 * KB + kb) * 2) * 64 + lane) * 8;
    #pragma unroll
    for (int i = 0; i < 8; ++i) {
        float v = s[i];
        u16 hi = f2bf(v);
        dst[base + i]       = hi;
        dst[base + 512 + i] = f2bf(v - bf2f(hi));
    }
}

// X -> A-frags for every encoder step: [t(128)][bt(16)][kb(4)][hl][64][8]
__global__ __launch_bounds__(256)
void pack_xa(const float* __restrict__ X, u16* __restrict__ dst)
{
    int idx  = blockIdx.x * 256 + threadIdx.x;       // 128*16*4*64 = 524288
    int lane = idx & 63;
    int t2   = idx >> 6;
    int kb   = t2 & 3;  t2 >>= 2;
    int bt   = t2 & 15; t2 >>= 4;
    int t    = t2;
    if (t >= TIN) return;
    int b = bt * 16 + (lane & 15);
    int d = kb * 32 + (lane >> 4) * 8;
    const float* s = X + (size_t)b * TIN * ND + (size_t)t * ND + d;
    size_t base = ((((size_t)(t * 16 + bt) * 4 + kb) * 2) * 64 + lane) * 8;
    #pragma unroll
    for (int i = 0; i < 8; ++i) {
        float v = s[i];
        u16 hi = f2bf(v);
        dst[base + i]       = hi;
        dst[base + 512 + i] = f2bf(v - bf2f(hi));
    }
}

__global__ __launch_bounds__(256)
void prep_bias(const float* __restrict__ bi, const float* __restrict__ bh,
               float4* __restrict__ dst)
{
    int j = blockIdx.x * 256 + threadIdx.x;
    if (j >= HID) return;
    dst[j] = make_float4(bi[j] + bh[j],
                         bi[HID + j] + bh[HID + j],
                         bi[2 * HID + j],
                         bh[2 * HID + j]);
}

// decoder steps>=1: x-bias folded with Wi@bo
__global__ __launch_bounds__(256)
void prep_bias2(const float* __restrict__ bi, const float* __restrict__ bh,
                const float* __restrict__ Wi, const float* __restrict__ bo,
                float4* __restrict__ dst)
{
    int j = blockIdx.x * 256 + threadIdx.x;
    if (j >= HID) return;
    float w[3];
    #pragma unroll
    for (int g = 0; g < 3; ++g) {
        float s = 0.f;
        const float* wr = Wi + (size_t)(g * HID + j) * ND;
        for (int o = 0; o < ND; ++o) s += wr[o] * bo[o];
        w[g] = s;
    }
    dst[j] = make_float4(bi[j] + bh[j] + w[0],
                         bi[HID + j] + bh[HID + j] + w[1],
                         bi[2 * HID + j] + w[2],
                         bh[2 * HID + j]);
}

__global__ __launch_bounds__(256)
void zero_u32(unsigned int* __restrict__ p, int n) {
    int i = blockIdx.x * 256 + threadIdx.x;
    if (i < n) p[i] = 0u;
}

// ================= two-level grid barrier (agent scope, cross-XCD safe) =====
__device__ __forceinline__ void gridbar(unsigned int* grp, unsigned int* root,
                                        unsigned int gtgt)
{
    __syncthreads();
    if (threadIdx.x == 0) {
        unsigned int gid = blockIdx.x & 15;
        if ((__hip_atomic_fetch_add(&grp[gid * 32], 1u, __ATOMIC_ACQ_REL,
                                    __HIP_MEMORY_SCOPE_AGENT) & 15u) == 15u)
            __hip_atomic_fetch_add(root, 1u, __ATOMIC_ACQ_REL,
                                   __HIP_MEMORY_SCOPE_AGENT);
        while (__hip_atomic_load(root, __ATOMIC_ACQUIRE,
                                 __HIP_MEMORY_SCOPE_AGENT) < gtgt)
            __builtin_amdgcn_s_sleep(2);
    }
    __syncthreads();
}

// ================= persistent cooperative kernel =============================
// grid 256 = (bt = bid&15, jq = bid>>4); 384 thr = 6 waves: (g = wv>>1, jh = wv&1)
__global__ __launch_bounds__(384, 2)
void seq_coop(const u16* __restrict__ encB, const u16* __restrict__ decB,
              const u16* __restrict__ WcB,  const u16* __restrict__ WpB,
              const u16* __restrict__ WoB,  const u16* __restrict__ xAe,
              u16* __restrict__ hA0, u16* __restrict__ hA1,
              u16* __restrict__ projA,
              const float4* __restrict__ biasE, const float4* __restrict__ biasD0,
              const float4* __restrict__ biasD1,
              const float* __restrict__ bp, const float* __restrict__ bo,
              float* __restrict__ d_out,
              unsigned int* __restrict__ grp, unsigned int* __restrict__ root)
{
    const int tid  = threadIdx.x;
    const int lane = tid & 63;
    const int wv   = tid >> 6;
    const int bid  = blockIdx.x;
    const int bt   = bid & 15;
    const int jq   = bid >> 4;
    const int g    = wv >> 1;
    const int jh   = wv & 1;
    const int jf16 = jq * 2 + jh;

    __shared__ u16   hstage[16 * 2 * 64 * 8];   // 32 KB: hA[bt] for this step
    __shared__ float gx[4][16][36];             // gate exchange r,z,nh,nx
    __shared__ float hprev[16][36];             // persistent h (this WG's 32 cols)

    for (int e = tid; e < 16 * 36; e += 384) (&hprev[0][0])[e] = 0.f;

    // persistent h-part weights: 16 kb x {hi,lo} = 128 VGPR
    s16x8 wH0[16], wH1[16];
    #pragma unroll
    for (int kb = 0; kb < 16; ++kb) {
        size_t b0 = ((((size_t)jf16 * 20 + kb) * 3 + g) * 2) * 512 + (size_t)lane * 8;
        wH0[kb] = *(const s16x8*)(encB + b0);
        wH1[kb] = *(const s16x8*)(encB + b0 + 512);
    }

    unsigned int tgt = 0;

    for (int s = 0; s < 192; ++s) {
        if (s == 128) {
            #pragma unroll
            for (int kb = 0; kb < 16; ++kb) {
                size_t b0 = ((((size_t)jf16 * 20 + kb) * 3 + g) * 2) * 512 + (size_t)lane * 8;
                wH0[kb] = *(const s16x8*)(decB + b0);
                wH1[kb] = *(const s16x8*)(decB + b0 + 512);
            }
        }
        const u16* hin  = (s & 1) ? hA1 : hA0;
        u16*       hout = (s & 1) ? hA0 : hA1;

        // stage h A-frags (32 KB) into LDS
        {
            const s16x8* src = (const s16x8*)(hin + (size_t)bt * 16384);
            s16x8* dst = (s16x8*)hstage;
            #pragma unroll
            for (int i = 0; i < 6; ++i) {
                int idx = tid + i * 384;
                if (idx < 2048) dst[idx] = src[idx];
            }
        }
        __syncthreads();

        f32x4 a0 = fz(), a1 = fz(), a2 = fz();
        f32x4 x0 = fz(), x1 = fz(), x2 = fz();

        // ---- h part: K 0..511 from LDS, weights from VGPR ----
        #pragma unroll
        for (int kb = 0; kb < 16; ++kb) {
            s16x8 ahi = *(const s16x8*)&hstage[(size_t)kb * 1024 + lane * 8];
            s16x8 alo = *(const s16x8*)&hstage[(size_t)kb * 1024 + 512 + lane * 8];
            a0 = mfma16(ahi, wH0[kb], a0);
            a1 = mfma16(ahi, wH1[kb], a1);
            a2 = mfma16(alo, wH0[kb], a2);
        }

        // ---- x part ----
        if (s <= 128) {
            int t = (s < 128) ? s : (TIN - 1);
            const u16* wsrc = (s < 128) ? encB : decB;
            const u16* xa = xAe + (size_t)(t * 16 + bt) * 4096;
            #pragma unroll
            for (int kb = 0; kb < 4; ++kb) {
                s16x8 ahi = *(const s16x8*)(xa + (size_t)kb * 1024 + lane * 8);
                s16x8 alo = *(const s16x8*)(xa + (size_t)kb * 1024 + 512 + lane * 8);
                size_t wb = ((((size_t)jf16 * 20 + 16 + kb) * 3 + g) * 2) * 512 + (size_t)lane * 8;
                s16x8 bhi = *(const s16x8*)(wsrc + wb);
                s16x8 blo = *(const s16x8*)(wsrc + wb + 512);
                if (g == 2) { x0 = mfma16(ahi, bhi, x0); x1 = mfma16(ahi, blo, x1); x2 = mfma16(alo, bhi, x2); }
                else        { a0 = mfma16(ahi, bhi, a0); a1 = mfma16(ahi, blo, a1); a2 = mfma16(alo, bhi, a2); }
            }
        } else {
            const u16* xa = projA + (size_t)((s - 129) & 1) * 131072 + (size_t)bt * 8192;
            #pragma unroll
            for (int kb = 0; kb < 8; ++kb) {
                s16x8 ahi = *(const s16x8*)(xa + (size_t)kb * 1024 + lane * 8);
                s16x8 alo = *(const s16x8*)(xa + (size_t)kb * 1024 + 512 + lane * 8);
                size_t wb = ((((size_t)jf16 * 8 + kb) * 3 + g) * 2) * 512 + (size_t)lane * 8;
                s16x8 bhi = *(const s16x8*)(WcB + wb);
                s16x8 blo = *(const s16x8*)(WcB + wb + 512);
                if (g == 2) { x0 = mfma16(ahi, bhi, x0); x1 = mfma16(ahi, blo, x1); x2 = mfma16(alo, bhi, x2); }
                else        { a0 = mfma16(ahi, bhi, a0); a1 = mfma16(ahi, blo, a1); a2 = mfma16(alo, bhi, a2); }
            }
        }

        f32x4 am = a0 + a1 + a2;
        f32x4 xm = x0 + x1 + x2;

        #pragma unroll
        for (int i = 0; i < 4; ++i) {
            int r  = (lane >> 4) * 4 + i;
            int lc = jh * 16 + (lane & 15);
            gx[g][r][lc] = am[i];
            if (g == 2) gx[3][r][lc] = xm[i];
        }
        __syncthreads();

        // ---- gates + h update (512 elems over 384 threads) ----
        {
            const float4* b4p = (s < 128) ? biasE : ((s == 128) ? biasD0 : biasD1);
            for (int e = tid; e < 512; e += 384) {
                int r = e >> 5, lc = e & 31;
                float4 b4 = b4p[jq * 32 + lc];
                float rg = 1.f / (1.f + expf(-(gx[0][r][lc] + b4.x)));
                float zg = 1.f / (1.f + expf(-(gx[1][r][lc] + b4.y)));
                float ng = tanhf(gx[3][r][lc] + b4.z + rg * (gx[2][r][lc] + b4.w));
                float hv = (1.f - zg) * ng + zg * hprev[r][lc];
                hprev[r][lc] = hv;
                gx[0][r][lc] = hv;
            }
        }
        __syncthreads();

        // wave0: emit this WG's 32 h-cols as A-frags (kb = jq) for next step
        if (wv == 0) {
            u16* dh = hout + ((size_t)(bt * 16 + jq) * 2) * 512 + (size_t)lane * 8;
            s16x8 vh, vl;
            #pragma unroll
            for (int i = 0; i < 8; ++i) {
                float v = gx[0][lane & 15][(lane >> 4) * 8 + i];
                u16 hi = f2bf(v);
                vh[i] = (short)hi;
                vl[i] = (short)f2bf(v - bf2f(hi));
            }
            *(s16x8*)dh = vh;
            *(s16x8*)(dh + 512) = vl;
        }
        tgt += 16; gridbar(grp, root, tgt);

        // ---- decoder: proj phase (+ piggybacked out[t-1]) ----
        if (s >= 128) {
            int t = s - 128, par = t & 1;
            if (bid < 128) {
                if (wv < 2) {
                    int btp = bid & 15, jqp = bid >> 4;       // jqp 0..7
                    int pf16 = jqp * 2 + wv;
                    f32x4 p0 = fz(), p1 = fz(), p2 = fz();
                    const u16* ha = hout + (size_t)btp * 16384;
                    const u16* wb = WpB + (size_t)pf16 * 16384;
                    #pragma unroll
                    for (int kb = 0; kb < 16; ++kb) {
                        s16x8 ahi = *(const s16x8*)(ha + (size_t)kb * 1024 + lane * 8);
                        s16x8 alo = *(const s16x8*)(ha + (size_t)kb * 1024 + 512 + lane * 8);
                        s16x8 bhi = *(const s16x8*)(wb + (size_t)kb * 1024 + lane * 8);
                        s16x8 blo = *(const s16x8*)(wb + (size_t)kb * 1024 + 512 + lane * 8);
                        p0 = mfma16(ahi, bhi, p0);
                        p1 = mfma16(ahi, blo, p1);
                        p2 = mfma16(alo, bhi, p2);
                    }
                    f32x4 pm = p0 + p1 + p2;
                    float bpv = bp[pf16 * 16 + (lane & 15)];
                    #pragma unroll
                    for (int i = 0; i < 4; ++i)
                        gx[0][(lane >> 4) * 4 + i][wv * 16 + (lane & 15)] = fmaxf(pm[i] + bpv, 0.f);
                }
            } else if (t >= 1 && wv == 0) {
                int ob = bid - 128;
                int bt2 = ob & 15, of16 = ob >> 4;
                f32x4 q0 = fz(), q1 = fz(), q2 = fz();
                const u16* pa = projA + (size_t)((t - 1) & 1) * 131072 + (size_t)bt2 * 8192;
                const u16* wb = WoB + (size_t)of16 * 8192;
                #pragma unroll
                for (int kb = 0; kb < 8; ++kb) {
                    s16x8 ahi = *(const s16x8*)(pa + (size_t)kb * 1024 + lane * 8);
                    s16x8 alo = *(const s16x8*)(pa + (size_t)kb * 1024 + 512 + lane * 8);
                    s16x8 bhi = *(const s16x8*)(wb + (size_t)kb * 1024 + lane * 8);
                    s16x8 blo = *(const s16x8*)(wb + (size_t)kb * 1024 + 512 + lane * 8);
                    q0 = mfma16(ahi, bhi, q0);
                    q1 = mfma16(ahi, blo, q1);
                    q2 = mfma16(alo, bhi, q2);
                }
                f32x4 qm = q0 + q1 + q2;
                float bov = bo[of16 * 16 + (lane & 15)];
                #pragma unroll
                for (int i = 0; i < 4; ++i) {
                    int b = bt2 * 16 + (lane >> 4) * 4 + i;
                    d_out[(size_t)b * (TOUT * ND) + (size_t)(t - 1) * ND + of16 * 16 + (lane & 15)] = qm[i] + bov;
                }
            }
            __syncthreads();
            if (bid < 128 && wv == 2) {
                int btp = bid & 15, jqp = bid >> 4;
                u16* dp = projA + (size_t)par * 131072 + (size_t)btp * 8192
                        + (size_t)jqp * 1024 + (size_t)lane * 8;
                s16x8 vh, vl;
                #pragma unroll
                for (int i = 0; i < 8; ++i) {
                    float v = gx[0][lane & 15][(lane >> 4) * 8 + i];
                    u16 hi = f2bf(v);
                    vh[i] = (short)hi;
                    vl[i] = (short)f2bf(v - bf2f(hi));
                }
                *(s16x8*)dp = vh;
                *(s16x8*)(dp + 512) = vl;
            }
            tgt += 16; gridbar(grp, root, tgt);
        }
    }

    // tail: out[63] (projA parity 1, written at s=191, visible after final barrier)
    if (bid >= 128 && wv == 0) {
        int ob = bid - 128;
        int bt2 = ob & 15, of16 = ob >> 4;
        f32x4 q0 = fz(), q1 = fz(), q2 = fz();
        const u16* pa = projA + (size_t)1 * 131072 + (size_t)bt2 * 8192;
        const u16* wb = WoB + (size_t)of16 * 8192;
        #pragma unroll
        for (int kb = 0; kb < 8; ++kb) {
            s16x8 ahi = *(const s16x8*)(pa + (size_t)kb * 1024 + lane * 8);
            s16x8 alo = *(const s16x8*)(pa + (size_t)kb * 1024 + 512 + lane * 8);
            s16x8 bhi = *(const s16x8*)(wb + (size_t)kb * 1024 + lane * 8);
            s16x8 blo = *(const s16x8*)(wb + (size_t)kb * 1024 + 512 + lane * 8);
            q0 = mfma16(ahi, bhi, q0);
            q1 = mfma16(ahi, blo, q1);
            q2 = mfma16(alo, bhi, q2);
        }
        f32x4 qm = q0 + q1 + q2;
        float bov = bo[of16 * 16 + (lane & 15)];
        #pragma unroll
        for (int i = 0; i < 4; ++i) {
            int b = bt2 * 16 + (lane >> 4) * 4 + i;
            d_out[(size_t)b * (TOUT * ND) + (size_t)63 * ND + of16 * 16 + (lane & 15)] = qm[i] + bov;
        }
    }
}

// ================= host =================
extern "C" void kernel_launch(void* const* d_in, const int* in_sizes, int n_in,
                              void* d_out, int out_size, void* d_ws, size_t ws_size,
                              hipStream_t stream)
{
    (void)in_sizes; (void)n_in; (void)out_size; (void)ws_size;

    const float* X      = (const float*)d_in[0];
    const float* enc_Wi = (const float*)d_in[1];
    const float* enc_Wh = (const float*)d_in[2];
    const float* enc_bi = (const float*)d_in[3];
    const float* enc_bh = (const float*)d_in[4];
    const float* dec_Wi = (const float*)d_in[5];
    const float* dec_Wh = (const float*)d_in[6];
    const float* dec_bi = (const float*)d_in[7];
    const float* dec_bh = (const float*)d_in[8];
    const float* Wp     = (const float*)d_in[9];
    const float* bp     = (const float*)d_in[10];
    const float* Wo     = (const float*)d_in[11];
    const float* bo     = (const float*)d_in[12];
    float* outp = (float*)d_out;

    char* w = (char*)d_ws;
    size_t off = 0;
    auto alloc = [&](size_t bytes) { void* p = w + off; off += (bytes + 255) & ~(size_t)255; return p; };

    u16* encB  = (u16*)alloc((size_t)32 * 20 * 3 * 2 * 512 * 2);   // 3.93 MB
    u16* decB  = (u16*)alloc((size_t)32 * 20 * 3 * 2 * 512 * 2);   // 3.93 MB
    u16* WcB   = (u16*)alloc((size_t)32 * 8 * 3 * 2 * 512 * 2);    // 1.57 MB
    u16* WpB   = (u16*)alloc((size_t)16 * 16 * 2 * 512 * 2);       // 0.5 MB
    u16* WoB   = (u16*)alloc((size_t)8 * 8 * 2 * 512 * 2);         // 128 KB
    u16* xAe   = (u16*)alloc((size_t)TIN * 16 * 4 * 2 * 512 * 2);  // 16.8 MB
    u16* hA0   = (u16*)alloc((size_t)16 * 16 * 2 * 512 * 2);       // 512 KB
    u16* hA1   = (u16*)alloc((size_t)16 * 16 * 2 * 512 * 2);
    u16* projA = (u16*)alloc((size_t)2 * 16 * 8 * 2 * 512 * 2);    // 512 KB
    float4* biasE  = (float4*)alloc(HID * 16);
    float4* biasD0 = (float4*)alloc(HID * 16);
    float4* biasD1 = (float4*)alloc(HID * 16);
    unsigned int* grp  = (unsigned int*)alloc((16 * 32 + 1) * 4);
    unsigned int* root = grp + 16 * 32;

    // prep (parallel, every call — deterministic)
    zero_u32<<<3, 256, 0, stream>>>(grp, 16 * 32 + 1);
    zero_u32<<<512, 256, 0, stream>>>((unsigned int*)hA0, 16 * 16 * 2 * 512 / 2);
    pack_gru_w<<<480, 256, 0, stream>>>(enc_Wh, enc_Wi, encB);
    pack_gru_w<<<480, 256, 0, stream>>>(dec_Wh, dec_Wi, decB);
    pack_wc<<<192, 256, 0, stream>>>(dec_Wi, Wo, WcB);
    pack_plain_w<<<64, 256, 0, stream>>>(Wp, HID, 16, 16, WpB);
    pack_plain_w<<<16, 256, 0, stream>>>(Wo, PROJD, 8, 8, WoB);
    pack_xa<<<2048, 256, 0, stream>>>(X, xAe);
    prep_bias<<<2, 256, 0, stream>>>(enc_bi, enc_bh, biasE);
    prep_bias<<<2, 256, 0, stream>>>(dec_bi, dec_bh, biasD0);
    prep_bias2<<<2, 256, 0, stream>>>(dec_bi, dec_bh, dec_Wi, bo, biasD1);

    void* args[] = { &encB, &decB, &WcB, &WpB, &WoB, &xAe, &hA0, &hA1, &projA,
                     &biasE, &biasD0, &biasD1, (void*)&bp, (void*)&bo, &outp,
                     &grp, &root };
    hipLaunchCooperativeKernel((void*)seq_coop, dim3(NWG), dim3(384), args, 0, stream);
}

// Round 4
// 4220.563 us; speedup vs baseline: 1.5005x; 1.5005x over previous
//
#include <hip/hip_runtime.h>
#include <math.h>

#define TIN   128
#define TOUT  64
#define ND    128
#define HID   512
#define PROJD 256
#define BSZ   256
#define NWG   256

using f32x4 = __attribute__((ext_vector_type(4))) float;
using s16x8 = __attribute__((ext_vector_type(8))) short;
typedef unsigned short u16;

__device__ __forceinline__ u16 f2bf(float x) {
    unsigned int u = __builtin_bit_cast(unsigned int, x);
    u += 0x7fffu + ((u >> 16) & 1u);          // RNE (finite values)
    return (u16)(u >> 16);
}
__device__ __forceinline__ float bf2f(u16 b) {
    unsigned int u = ((unsigned int)b) << 16;
    return __builtin_bit_cast(float, u);
}
__device__ __forceinline__ f32x4 mfma16(s16x8 a, s16x8 b, f32x4 c) {
    return __builtin_amdgcn_mfma_f32_16x16x32_bf16(a, b, c, 0, 0, 0);
}
__device__ __forceinline__ f32x4 fz() { return (f32x4){0.f, 0.f, 0.f, 0.f}; }

// ================= prep kernels (parallel, off critical path) =================

// GRU weights: [jf16(32)][kb(20: 0-15 Wh,16-19 Wi)][g(3)][hl(2)][64][8]
__global__ __launch_bounds__(256)
void pack_gru_w(const float* __restrict__ Wh, const float* __restrict__ Wi,
                u16* __restrict__ dst)
{
    int idx  = blockIdx.x * 256 + threadIdx.x;       // 32*20*3*64 = 122880
    int lane = idx & 63;
    int t    = idx >> 6;
    int g    = t % 3;  t /= 3;
    int kb   = t % 20; t /= 20;
    int jf16 = t;
    if (jf16 >= 32) return;
    int row = g * HID + jf16 * 16 + (lane & 15);
    int kk  = kb * 32 + (lane >> 4) * 8;
    float v[8];
    if (kb < 16) { const float* s = Wh + (size_t)row * HID + kk;
        #pragma unroll
        for (int i = 0; i < 8; ++i) v[i] = s[i];
    } else { const float* s = Wi + (size_t)row * ND + (kk - HID);
        #pragma unroll
        for (int i = 0; i < 8; ++i) v[i] = s[i];
    }
    size_t base = ((((size_t)(jf16 * 20 + kb) * 3 + g) * 2) * 64 + lane) * 8;
    #pragma unroll
    for (int i = 0; i < 8; ++i) {
        u16 hi = f2bf(v[i]);
        dst[base + i]       = hi;
        dst[base + 512 + i] = f2bf(v[i] - bf2f(hi));
    }
}

// Wc = dec_Wi @ Wo  [1536][256] -> frags [jf16(32)][kb(8)][g(3)][hl][64][8]
__global__ __launch_bounds__(256)
void pack_wc(const float* __restrict__ Wi, const float* __restrict__ Wo,
             u16* __restrict__ dst)
{
    int idx  = blockIdx.x * 256 + threadIdx.x;       // 32*8*3*64 = 49152
    int lane = idx & 63;
    int t    = idx >> 6;
    int g    = t % 3; t /= 3;
    int kb   = t % 8; t /= 8;
    int jf16 = t;
    if (jf16 >= 32) return;
    int row = g * HID + jf16 * 16 + (lane & 15);
    int p0  = kb * 32 + (lane >> 4) * 8;
    float acc[8] = {0.f,0.f,0.f,0.f,0.f,0.f,0.f,0.f};
    for (int o = 0; o < ND; ++o) {
        float wi = Wi[(size_t)row * ND + o];
        const float* wo = Wo + (size_t)o * PROJD + p0;
        #pragma unroll
        for (int i = 0; i < 8; ++i) acc[i] += wi * wo[i];
    }
    size_t base = ((((size_t)(jf16 * 8 + kb) * 3 + g) * 2) * 64 + lane) * 8;
    #pragma unroll
    for (int i = 0; i < 8; ++i) {
        u16 hi = f2bf(acc[i]);
        dst[base + i]       = hi;
        dst[base + 512 + i] = f2bf(acc[i] - bf2f(hi));
    }
}

// plain weight (no gates): [jf16][kb][hl][64][8]
__global__ __launch_bounds__(256)
void pack_plain_w(const float* __restrict__ W, int K, int NF, int KB,
                  u16* __restrict__ dst)
{
    int idx  = blockIdx.x * 256 + threadIdx.x;
    int lane = idx & 63;
    int t    = idx >> 6;
    int kb   = t % KB;
    int jf16 = t / KB;
    if (jf16 >= NF) return;
    int row = jf16 * 16 + (lane & 15);
    int kk  = kb * 32 + (lane >> 4) * 8;
    const float* s = W + (size_t)row * K + kk;
    size_t base = (((size_t)(jf16 * KB + kb) * 2) * 64 + lane) * 8;
    #pragma unroll
    for (int i = 0; i < 8; ++i) {
        float v = s[i];
        u16 hi = f2bf(v);
        dst[base + i]       = hi;
        dst[base + 512 + i] = f2bf(v - bf2f(hi));
    }
}

// X -> A-frags for every encoder step: [t(128)][bt(16)][kb(4)][hl][64][8]
__global__ __launch_bounds__(256)
void pack_xa(const float* __restrict__ X, u16* __restrict__ dst)
{
    int idx  = blockIdx.x * 256 + threadIdx.x;       // 128*16*4*64 = 524288
    int lane = idx & 63;
    int t2   = idx >> 6;
    int kb   = t2 & 3;  t2 >>= 2;
    int bt   = t2 & 15; t2 >>= 4;
    int t    = t2;
    if (t >= TIN) return;
    int b = bt * 16 + (lane & 15);
    int d = kb * 32 + (lane >> 4) * 8;
    const float* s = X + (size_t)b * TIN * ND + (size_t)t * ND + d;
    size_t base = ((((size_t)(t * 16 + bt) * 4 + kb) * 2) * 64 + lane) * 8;
    #pragma unroll
    for (int i = 0; i < 8; ++i) {
        float v = s[i];
        u16 hi = f2bf(v);
        dst[base + i]       = hi;
        dst[base + 512 + i] = f2bf(v - bf2f(hi));
    }
}

__global__ __launch_bounds__(256)
void prep_bias(const float* __restrict__ bi, const float* __restrict__ bh,
               float4* __restrict__ dst)
{
    int j = blockIdx.x * 256 + threadIdx.x;
    if (j >= HID) return;
    dst[j] = make_float4(bi[j] + bh[j],
                         bi[HID + j] + bh[HID + j],
                         bi[2 * HID + j],
                         bh[2 * HID + j]);
}

// decoder steps>=1: x-bias folded with Wi@bo
__global__ __launch_bounds__(256)
void prep_bias2(const float* __restrict__ bi, const float* __restrict__ bh,
                const float* __restrict__ Wi, const float* __restrict__ bo,
                float4* __restrict__ dst)
{
    int j = blockIdx.x * 256 + threadIdx.x;
    if (j >= HID) return;
    float w[3];
    #pragma unroll
    for (int g = 0; g < 3; ++g) {
        float s = 0.f;
        const float* wr = Wi + (size_t)(g * HID + j) * ND;
        for (int o = 0; o < ND; ++o) s += wr[o] * bo[o];
        w[g] = s;
    }
    dst[j] = make_float4(bi[j] + bh[j] + w[0],
                         bi[HID + j] + bh[HID + j] + w[1],
                         bi[2 * HID + j] + w[2],
                         bh[2 * HID + j]);
}

__global__ __launch_bounds__(256)
void zero_u32(unsigned int* __restrict__ p, int n) {
    int i = blockIdx.x * 256 + threadIdx.x;
    if (i < n) p[i] = 0u;
}

// ================= per-bt point-to-point sync =================
// cnt[bt]  at sync + bt*256        : +1 per WG per GRU step (16/step)
// cnt2[bt] at sync + bt*256 + 128  : +1 per proj-WG per decoder step (8/step)
__device__ __forceinline__ unsigned int syncload(const unsigned int* p) {
    return __hip_atomic_load(p, __ATOMIC_ACQUIRE, __HIP_MEMORY_SCOPE_AGENT);
}
__device__ __forceinline__ void syncadd(unsigned int* p) {
    __hip_atomic_fetch_add(p, 1u, __ATOMIC_RELEASE, __HIP_MEMORY_SCOPE_AGENT);
}

// ================= persistent cooperative kernel =============================
// grid 256 = (bt = bid&15, jq = bid>>4); 384 thr = 6 waves: (g = wv>>1, jh = wv&1)
__global__ __launch_bounds__(384, 2)
void seq_coop(const u16* __restrict__ encB, const u16* __restrict__ decB,
              const u16* __restrict__ WcB,  const u16* __restrict__ WpB,
              const u16* __restrict__ WoB,  const u16* __restrict__ xAe,
              u16* __restrict__ hA0, u16* __restrict__ hA1,
              u16* __restrict__ projA,
              const float4* __restrict__ biasE, const float4* __restrict__ biasD0,
              const float4* __restrict__ biasD1,
              const float* __restrict__ bp, const float* __restrict__ bo,
              float* __restrict__ d_out,
              unsigned int* __restrict__ syncb)
{
    const int tid  = threadIdx.x;
    const int lane = tid & 63;
    const int wv   = tid >> 6;
    const int bid  = blockIdx.x;
    const int bt   = bid & 15;
    const int jq   = bid >> 4;
    const int g    = wv >> 1;
    const int jh   = wv & 1;
    const int jf16 = jq * 2 + jh;

    unsigned int* cnt  = syncb + bt * 256;
    unsigned int* cnt2 = syncb + bt * 256 + 128;

    __shared__ u16   hstage[16 * 2 * 64 * 8];   // 32 KB: hA[bt] for this step
    __shared__ float gx[4][16][36];             // gate exchange r,z,nh,nx
    __shared__ float hprev[16][36];             // persistent h (this WG's 32 cols)

    for (int e = tid; e < 16 * 36; e += 384) (&hprev[0][0])[e] = 0.f;

    // persistent h-part weights: 16 kb x {hi,lo} = 128 VGPR
    s16x8 wH0[16], wH1[16];
    #pragma unroll
    for (int kb = 0; kb < 16; ++kb) {
        size_t b0 = ((((size_t)jf16 * 20 + kb) * 3 + g) * 2) * 512 + (size_t)lane * 8;
        wH0[kb] = *(const s16x8*)(encB + b0);
        wH1[kb] = *(const s16x8*)(encB + b0 + 512);
    }

    for (int s = 0; s < 192; ++s) {
        if (s == 128) {
            #pragma unroll
            for (int kb = 0; kb < 16; ++kb) {
                size_t b0 = ((((size_t)jf16 * 20 + kb) * 3 + g) * 2) * 512 + (size_t)lane * 8;
                wH0[kb] = *(const s16x8*)(decB + b0);
                wH1[kb] = *(const s16x8*)(decB + b0 + 512);
            }
        }
        const u16* hin  = (s & 1) ? hA1 : hA0;
        u16*       hout = (s & 1) ? hA0 : hA1;

        // ---- start-of-step wait: h(s) frags ready (+ proj frags for x-path) ----
        if (s > 0) {
            if (tid == 0) {
                unsigned int tc = 16u * (unsigned)s;
                while (syncload(cnt) < tc) __builtin_amdgcn_s_sleep(4);
                if (s >= 129) {
                    unsigned int t2 = 8u * (unsigned)(s - 128);
                    while (syncload(cnt2) < t2) __builtin_amdgcn_s_sleep(4);
                }
            }
            __syncthreads();
        }

        // stage h A-frags (32 KB) into LDS
        {
            const s16x8* src = (const s16x8*)(hin + (size_t)bt * 16384);
            s16x8* dst = (s16x8*)hstage;
            #pragma unroll
            for (int i = 0; i < 6; ++i) {
                int idx = tid + i * 384;
                if (idx < 2048) dst[idx] = src[idx];
            }
        }
        __syncthreads();

        f32x4 a0 = fz(), a1 = fz(), a2 = fz();
        f32x4 x0 = fz(), x1 = fz(), x2 = fz();

        // ---- h part: K 0..511 from LDS, weights from VGPR ----
        #pragma unroll
        for (int kb = 0; kb < 16; ++kb) {
            s16x8 ahi = *(const s16x8*)&hstage[(size_t)kb * 1024 + lane * 8];
            s16x8 alo = *(const s16x8*)&hstage[(size_t)kb * 1024 + 512 + lane * 8];
            a0 = mfma16(ahi, wH0[kb], a0);
            a1 = mfma16(ahi, wH1[kb], a1);
            a2 = mfma16(alo, wH0[kb], a2);
        }

        // ---- x part ----
        if (s <= 128) {
            int t = (s < 128) ? s : (TIN - 1);
            const u16* wsrc = (s < 128) ? encB : decB;
            const u16* xa = xAe + (size_t)(t * 16 + bt) * 4096;
            #pragma unroll
            for (int kb = 0; kb < 4; ++kb) {
                s16x8 ahi = *(const s16x8*)(xa + (size_t)kb * 1024 + lane * 8);
                s16x8 alo = *(const s16x8*)(xa + (size_t)kb * 1024 + 512 + lane * 8);
                size_t wb = ((((size_t)jf16 * 20 + 16 + kb) * 3 + g) * 2) * 512 + (size_t)lane * 8;
                s16x8 bhi = *(const s16x8*)(wsrc + wb);
                s16x8 blo = *(const s16x8*)(wsrc + wb + 512);
                if (g == 2) { x0 = mfma16(ahi, bhi, x0); x1 = mfma16(ahi, blo, x1); x2 = mfma16(alo, bhi, x2); }
                else        { a0 = mfma16(ahi, bhi, a0); a1 = mfma16(ahi, blo, a1); a2 = mfma16(alo, bhi, a2); }
            }
        } else {
            const u16* xa = projA + (size_t)((s - 129) & 1) * 131072 + (size_t)bt * 8192;
            #pragma unroll
            for (int kb = 0; kb < 8; ++kb) {
                s16x8 ahi = *(const s16x8*)(xa + (size_t)kb * 1024 + lane * 8);
                s16x8 alo = *(const s16x8*)(xa + (size_t)kb * 1024 + 512 + lane * 8);
                size_t wb = ((((size_t)jf16 * 8 + kb) * 3 + g) * 2) * 512 + (size_t)lane * 8;
                s16x8 bhi = *(const s16x8*)(WcB + wb);
                s16x8 blo = *(const s16x8*)(WcB + wb + 512);
                if (g == 2) { x0 = mfma16(ahi, bhi, x0); x1 = mfma16(ahi, blo, x1); x2 = mfma16(alo, bhi, x2); }
                else        { a0 = mfma16(ahi, bhi, a0); a1 = mfma16(ahi, blo, a1); a2 = mfma16(alo, bhi, a2); }
            }
        }

        f32x4 am = a0 + a1 + a2;
        f32x4 xm = x0 + x1 + x2;

        #pragma unroll
        for (int i = 0; i < 4; ++i) {
            int r  = (lane >> 4) * 4 + i;
            int lc = jh * 16 + (lane & 15);
            gx[g][r][lc] = am[i];
            if (g == 2) gx[3][r][lc] = xm[i];
        }
        __syncthreads();

        // ---- gates + h update (512 elems over 384 threads) ----
        {
            const float4* b4p = (s < 128) ? biasE : ((s == 128) ? biasD0 : biasD1);
            for (int e = tid; e < 512; e += 384) {
                int r = e >> 5, lc = e & 31;
                float4 b4 = b4p[jq * 32 + lc];
                float rg = 1.f / (1.f + expf(-(gx[0][r][lc] + b4.x)));
                float zg = 1.f / (1.f + expf(-(gx[1][r][lc] + b4.y)));
                float ng = tanhf(gx[3][r][lc] + b4.z + rg * (gx[2][r][lc] + b4.w));
                float hv = (1.f - zg) * ng + zg * hprev[r][lc];
                hprev[r][lc] = hv;
                gx[0][r][lc] = hv;
            }
        }
        __syncthreads();

        // wave0: emit this WG's 32 h-cols as A-frags (kb = jq) for next step
        if (wv == 0) {
            u16* dh = hout + ((size_t)(bt * 16 + jq) * 2) * 512 + (size_t)lane * 8;
            s16x8 vh, vl;
            #pragma unroll
            for (int i = 0; i < 8; ++i) {
                float v = gx[0][lane & 15][(lane >> 4) * 8 + i];
                u16 hi = f2bf(v);
                vh[i] = (short)hi;
                vl[i] = (short)f2bf(v - bf2f(hi));
            }
            *(s16x8*)dh = vh;
            *(s16x8*)(dh + 512) = vl;
        }
        __syncthreads();                    // drain frag stores (vmcnt(0) at barrier)
        if (tid == 0) syncadd(cnt);         // publish h(s+1)

        // ---- decoder: proj phase (+ piggybacked out[t-1]) ----
        if (s >= 128) {
            int t = s - 128, par = t & 1;
            // mid-phase wait
            if (tid == 0) {
                if (jq < 8) {
                    unsigned int tc = 16u * (unsigned)(s + 1);
                    while (syncload(cnt) < tc) __builtin_amdgcn_s_sleep(4);
                } else if (t >= 1) {
                    unsigned int t2 = 8u * (unsigned)t;
                    while (syncload(cnt2) < t2) __builtin_amdgcn_s_sleep(4);
                }
            }
            __syncthreads();

            if (jq < 8) {
                if (wv < 2) {
                    int pf16 = jq * 2 + wv;
                    f32x4 p0 = fz(), p1 = fz(), p2 = fz();
                    const u16* ha = hout + (size_t)bt * 16384;
                    const u16* wb = WpB + (size_t)pf16 * 16384;
                    #pragma unroll
                    for (int kb = 0; kb < 16; ++kb) {
                        s16x8 ahi = *(const s16x8*)(ha + (size_t)kb * 1024 + lane * 8);
                        s16x8 alo = *(const s16x8*)(ha + (size_t)kb * 1024 + 512 + lane * 8);
                        s16x8 bhi = *(const s16x8*)(wb + (size_t)kb * 1024 + lane * 8);
                        s16x8 blo = *(const s16x8*)(wb + (size_t)kb * 1024 + 512 + lane * 8);
                        p0 = mfma16(ahi, bhi, p0);
                        p1 = mfma16(ahi, blo, p1);
                        p2 = mfma16(alo, bhi, p2);
                    }
                    f32x4 pm = p0 + p1 + p2;
                    float bpv = bp[pf16 * 16 + (lane & 15)];
                    #pragma unroll
                    for (int i = 0; i < 4; ++i)
                        gx[0][(lane >> 4) * 4 + i][wv * 16 + (lane & 15)] = fmaxf(pm[i] + bpv, 0.f);
                }
            } else if (t >= 1 && wv == 0) {
                int of16 = jq - 8;
                f32x4 q0 = fz(), q1 = fz(), q2 = fz();
                const u16* pa = projA + (size_t)((t - 1) & 1) * 131072 + (size_t)bt * 8192;
                const u16* wb = WoB + (size_t)of16 * 8192;
                #pragma unroll
                for (int kb = 0; kb < 8; ++kb) {
                    s16x8 ahi = *(const s16x8*)(pa + (size_t)kb * 1024 + lane * 8);
                    s16x8 alo = *(const s16x8*)(pa + (size_t)kb * 1024 + 512 + lane * 8);
                    s16x8 bhi = *(const s16x8*)(wb + (size_t)kb * 1024 + lane * 8);
                    s16x8 blo = *(const s16x8*)(wb + (size_t)kb * 1024 + 512 + lane * 8);
                    q0 = mfma16(ahi, bhi, q0);
                    q1 = mfma16(ahi, blo, q1);
                    q2 = mfma16(alo, bhi, q2);
                }
                f32x4 qm = q0 + q1 + q2;
                float bov = bo[of16 * 16 + (lane & 15)];
                #pragma unroll
                for (int i = 0; i < 4; ++i) {
                    int b = bt * 16 + (lane >> 4) * 4 + i;
                    d_out[(size_t)b * (TOUT * ND) + (size_t)(t - 1) * ND + of16 * 16 + (lane & 15)] = qm[i] + bov;
                }
            }
            __syncthreads();
            if (jq < 8 && wv == 2) {
                u16* dp = projA + (size_t)par * 131072 + (size_t)bt * 8192
                        + (size_t)jq * 1024 + (size_t)lane * 8;
                s16x8 vh, vl;
                #pragma unroll
                for (int i = 0; i < 8; ++i) {
                    float v = gx[0][lane & 15][(lane >> 4) * 8 + i];
                    u16 hi = f2bf(v);
                    vh[i] = (short)hi;
                    vl[i] = (short)f2bf(v - bf2f(hi));
                }
                *(s16x8*)dp = vh;
                *(s16x8*)(dp + 512) = vl;
            }
            __syncthreads();                // drain projA stores
            if (jq < 8 && tid == 0) syncadd(cnt2);   // publish proj(t)
        }
    }

    // tail: out[63] reads proj(63) (parity 1)
    if (jq >= 8) {
        if (tid == 0)
            while (syncload(cnt2) < 8u * (unsigned)TOUT) __builtin_amdgcn_s_sleep(4);
        __syncthreads();
        if (wv == 0) {
            int of16 = jq - 8;
            f32x4 q0 = fz(), q1 = fz(), q2 = fz();
            const u16* pa = projA + (size_t)1 * 131072 + (size_t)bt * 8192;
            const u16* wb = WoB + (size_t)of16 * 8192;
            #pragma unroll
            for (int kb = 0; kb < 8; ++kb) {
                s16x8 ahi = *(const s16x8*)(pa + (size_t)kb * 1024 + lane * 8);
                s16x8 alo = *(const s16x8*)(pa + (size_t)kb * 1024 + 512 + lane * 8);
                s16x8 bhi = *(const s16x8*)(wb + (size_t)kb * 1024 + lane * 8);
                s16x8 blo = *(const s16x8*)(wb + (size_t)kb * 1024 + 512 + lane * 8);
                q0 = mfma16(ahi, bhi, q0);
                q1 = mfma16(ahi, blo, q1);
                q2 = mfma16(alo, bhi, q2);
            }
            f32x4 qm = q0 + q1 + q2;
            float bov = bo[of16 * 16 + (lane & 15)];
            #pragma unroll
            for (int i = 0; i < 4; ++i) {
                int b = bt * 16 + (lane >> 4) * 4 + i;
                d_out[(size_t)b * (TOUT * ND) + (size_t)63 * ND + of16 * 16 + (lane & 15)] = qm[i] + bov;
            }
        }
    }
}

// ================= host =================
extern "C" void kernel_launch(void* const* d_in, const int* in_sizes, int n_in,
                              void* d_out, int out_size, void* d_ws, size_t ws_size,
                              hipStream_t stream)
{
    (void)in_sizes; (void)n_in; (void)out_size; (void)ws_size;

    const float* X      = (const float*)d_in[0];
    const float* enc_Wi = (const float*)d_in[1];
    const float* enc_Wh = (const float*)d_in[2];
    const float* enc_bi = (const float*)d_in[3];
    const float* enc_bh = (const float*)d_in[4];
    const float* dec_Wi = (const float*)d_in[5];
    const float* dec_Wh = (const float*)d_in[6];
    const float* dec_bi = (const float*)d_in[7];
    const float* dec_bh = (const float*)d_in[8];
    const float* Wp     = (const float*)d_in[9];
    const float* bp     = (const float*)d_in[10];
    const float* Wo     = (const float*)d_in[11];
    const float* bo     = (const float*)d_in[12];
    float* outp = (float*)d_out;

    char* w = (char*)d_ws;
    size_t off = 0;
    auto alloc = [&](size_t bytes) { void* p = w + off; off += (bytes + 255) & ~(size_t)255; return p; };

    u16* encB  = (u16*)alloc((size_t)32 * 20 * 3 * 2 * 512 * 2);   // 3.93 MB
    u16* decB  = (u16*)alloc((size_t)32 * 20 * 3 * 2 * 512 * 2);   // 3.93 MB
    u16* WcB   = (u16*)alloc((size_t)32 * 8 * 3 * 2 * 512 * 2);    // 1.57 MB
    u16* WpB   = (u16*)alloc((size_t)16 * 16 * 2 * 512 * 2);       // 0.5 MB
    u16* WoB   = (u16*)alloc((size_t)8 * 8 * 2 * 512 * 2);         // 128 KB
    u16* xAe   = (u16*)alloc((size_t)TIN * 16 * 4 * 2 * 512 * 2);  // 16.8 MB
    u16* hA0   = (u16*)alloc((size_t)16 * 16 * 2 * 512 * 2);       // 512 KB
    u16* hA1   = (u16*)alloc((size_t)16 * 16 * 2 * 512 * 2);
    u16* projA = (u16*)alloc((size_t)2 * 16 * 8 * 2 * 512 * 2);    // 512 KB
    float4* biasE  = (float4*)alloc(HID * 16);
    float4* biasD0 = (float4*)alloc(HID * 16);
    float4* biasD1 = (float4*)alloc(HID * 16);
    unsigned int* syncb = (unsigned int*)alloc(16 * 256 * 4);      // 16 KB

    // prep (parallel, every call — deterministic)
    zero_u32<<<16, 256, 0, stream>>>(syncb, 16 * 256);
    zero_u32<<<512, 256, 0, stream>>>((unsigned int*)hA0, 16 * 16 * 2 * 512 / 2);
    pack_gru_w<<<480, 256, 0, stream>>>(enc_Wh, enc_Wi, encB);
    pack_gru_w<<<480, 256, 0, stream>>>(dec_Wh, dec_Wi, decB);
    pack_wc<<<192, 256, 0, stream>>>(dec_Wi, Wo, WcB);
    pack_plain_w<<<64, 256, 0, stream>>>(Wp, HID, 16, 16, WpB);
    pack_plain_w<<<16, 256, 0, stream>>>(Wo, PROJD, 8, 8, WoB);
    pack_xa<<<2048, 256, 0, stream>>>(X, xAe);
    prep_bias<<<2, 256, 0, stream>>>(enc_bi, enc_bh, biasE);
    prep_bias<<<2, 256, 0, stream>>>(dec_bi, dec_bh, biasD0);
    prep_bias2<<<2, 256, 0, stream>>>(dec_bi, dec_bh, dec_Wi, bo, biasD1);

    void* args[] = { &encB, &decB, &WcB, &WpB, &WoB, &xAe, &hA0, &hA1, &projA,
                     &biasE, &biasD0, &biasD1, (void*)&bp, (void*)&bo, &outp,
                     &syncb };
    hipLaunchCooperativeKernel((void*)seq_coop, dim3(NWG), dim3(384), args, 0, stream);
}

// Round 5
// 1892.684 us; speedup vs baseline: 3.3461x; 2.2299x over previous
//
#include <hip/hip_runtime.h>
#include <math.h>

#define TIN   128
#define TOUT  64
#define ND    128
#define HID   512
#define PROJD 256
#define BSZ   256
#define NWG   256

using f32x4 = __attribute__((ext_vector_type(4))) float;
using s16x8 = __attribute__((ext_vector_type(8))) short;
using u64x2 = __attribute__((ext_vector_type(2))) unsigned long long;
typedef unsigned short u16;
typedef unsigned long long u64;

__device__ __forceinline__ u16 f2bf(float x) {
    unsigned int u = __builtin_bit_cast(unsigned int, x);
    u += 0x7fffu + ((u >> 16) & 1u);          // RNE (finite values)
    return (u16)(u >> 16);
}
__device__ __forceinline__ float bf2f(u16 b) {
    unsigned int u = ((unsigned int)b) << 16;
    return __builtin_bit_cast(float, u);
}
__device__ __forceinline__ f32x4 mfma16(s16x8 a, s16x8 b, f32x4 c) {
    return __builtin_amdgcn_mfma_f32_16x16x32_bf16(a, b, c, 0, 0, 0);
}
__device__ __forceinline__ f32x4 fz() { return (f32x4){0.f, 0.f, 0.f, 0.f}; }

// ---- coherent (LLC-level) data movement: relaxed agent-scope atomics ----
// Lower to plain global load/store with L2-bypass cache bits: no buffer_inv,
// no buffer_wbl2, XCD L2 stays warm for weights.
__device__ __forceinline__ u64 ld8(const u64* p) {
    return __hip_atomic_load(p, __ATOMIC_RELAXED, __HIP_MEMORY_SCOPE_AGENT);
}
__device__ __forceinline__ void st8(u64* p, u64 v) {
    __hip_atomic_store(p, v, __ATOMIC_RELAXED, __HIP_MEMORY_SCOPE_AGENT);
}
__device__ __forceinline__ unsigned int syncload(const unsigned int* p) {
    return __hip_atomic_load(p, __ATOMIC_RELAXED, __HIP_MEMORY_SCOPE_AGENT);
}
__device__ __forceinline__ void syncadd(unsigned int* p) {
    __hip_atomic_fetch_add(p, 1u, __ATOMIC_RELAXED, __HIP_MEMORY_SCOPE_AGENT);
}

// ================= prep kernels (parallel, off critical path) =================

// GRU weights: [jf16(32)][kb(20: 0-15 Wh,16-19 Wi)][g(3)][hl(2)][64][8]
__global__ __launch_bounds__(256)
void pack_gru_w(const float* __restrict__ Wh, const float* __restrict__ Wi,
                u16* __restrict__ dst)
{
    int idx  = blockIdx.x * 256 + threadIdx.x;       // 32*20*3*64 = 122880
    int lane = idx & 63;
    int t    = idx >> 6;
    int g    = t % 3;  t /= 3;
    int kb   = t % 20; t /= 20;
    int jf16 = t;
    if (jf16 >= 32) return;
    int row = g * HID + jf16 * 16 + (lane & 15);
    int kk  = kb * 32 + (lane >> 4) * 8;
    float v[8];
    if (kb < 16) { const float* s = Wh + (size_t)row * HID + kk;
        #pragma unroll
        for (int i = 0; i < 8; ++i) v[i] = s[i];
    } else { const float* s = Wi + (size_t)row * ND + (kk - HID);
        #pragma unroll
        for (int i = 0; i < 8; ++i) v[i] = s[i];
    }
    size_t base = ((((size_t)(jf16 * 20 + kb) * 3 + g) * 2) * 64 + lane) * 8;
    #pragma unroll
    for (int i = 0; i < 8; ++i) {
        u16 hi = f2bf(v[i]);
        dst[base + i]       = hi;
        dst[base + 512 + i] = f2bf(v[i] - bf2f(hi));
    }
}

// Wc = dec_Wi @ Wo  [1536][256] -> frags [jf16(32)][kb(8)][g(3)][hl][64][8]
__global__ __launch_bounds__(256)
void pack_wc(const float* __restrict__ Wi, const float* __restrict__ Wo,
             u16* __restrict__ dst)
{
    int idx  = blockIdx.x * 256 + threadIdx.x;       // 32*8*3*64 = 49152
    int lane = idx & 63;
    int t    = idx >> 6;
    int g    = t % 3; t /= 3;
    int kb   = t % 8; t /= 8;
    int jf16 = t;
    if (jf16 >= 32) return;
    int row = g * HID + jf16 * 16 + (lane & 15);
    int p0  = kb * 32 + (lane >> 4) * 8;
    float acc[8] = {0.f,0.f,0.f,0.f,0.f,0.f,0.f,0.f};
    for (int o = 0; o < ND; ++o) {
        float wi = Wi[(size_t)row * ND + o];
        const float* wo = Wo + (size_t)o * PROJD + p0;
        #pragma unroll
        for (int i = 0; i < 8; ++i) acc[i] += wi * wo[i];
    }
    size_t base = ((((size_t)(jf16 * 8 + kb) * 3 + g) * 2) * 64 + lane) * 8;
    #pragma unroll
    for (int i = 0; i < 8; ++i) {
        u16 hi = f2bf(acc[i]);
        dst[base + i]       = hi;
        dst[base + 512 + i] = f2bf(acc[i] - bf2f(hi));
    }
}

// plain weight (no gates): [jf16][kb][hl][64][8]
__global__ __launch_bounds__(256)
void pack_plain_w(const float* __restrict__ W, int K, int NF, int KB,
                  u16* __restrict__ dst)
{
    int idx  = blockIdx.x * 256 + threadIdx.x;
    int lane = idx & 63;
    int t    = idx >> 6;
    int kb   = t % KB;
    int jf16 = t / KB;
    if (jf16 >= NF) return;
    int row = jf16 * 16 + (lane & 15);
    int kk  = kb * 32 + (lane >> 4) * 8;
    const float* s = W + (size_t)row * K + kk;
    size_t base = (((size_t)(jf16 * KB + kb) * 2) * 64 + lane) * 8;
    #pragma unroll
    for (int i = 0; i < 8; ++i) {
        float v = s[i];
        u16 hi = f2bf(v);
        dst[base + i]       = hi;
        dst[base + 512 + i] = f2bf(v - bf2f(hi));
    }
}

// X -> A-frags for every encoder step: [t(128)][bt(16)][kb(4)][hl][64][8]
__global__ __launch_bounds__(256)
void pack_xa(const float* __restrict__ X, u16* __restrict__ dst)
{
    int idx  = blockIdx.x * 256 + threadIdx.x;       // 128*16*4*64 = 524288
    int lane = idx & 63;
    int t2   = idx >> 6;
    int kb   = t2 & 3;  t2 >>= 2;
    int bt   = t2 & 15; t2 >>= 4;
    int t    = t2;
    if (t >= TIN) return;
    int b = bt * 16 + (lane & 15);
    int d = kb * 32 + (lane >> 4) * 8;
    const float* s = X + (size_t)b * TIN * ND + (size_t)t * ND + d;
    size_t base = ((((size_t)(t * 16 + bt) * 4 + kb) * 2) * 64 + lane) * 8;
    #pragma unroll
    for (int i = 0; i < 8; ++i) {
        float v = s[i];
        u16 hi = f2bf(v);
        dst[base + i]       = hi;
        dst[base + 512 + i] = f2bf(v - bf2f(hi));
    }
}

__global__ __launch_bounds__(256)
void prep_bias(const float* __restrict__ bi, const float* __restrict__ bh,
               float4* __restrict__ dst)
{
    int j = blockIdx.x * 256 + threadIdx.x;
    if (j >= HID) return;
    dst[j] = make_float4(bi[j] + bh[j],
                         bi[HID + j] + bh[HID + j],
                         bi[2 * HID + j],
                         bh[2 * HID + j]);
}

// decoder steps>=1: x-bias folded with Wi@bo
__global__ __launch_bounds__(256)
void prep_bias2(const float* __restrict__ bi, const float* __restrict__ bh,
                const float* __restrict__ Wi, const float* __restrict__ bo,
                float4* __restrict__ dst)
{
    int j = blockIdx.x * 256 + threadIdx.x;
    if (j >= HID) return;
    float w[3];
    #pragma unroll
    for (int g = 0; g < 3; ++g) {
        float s = 0.f;
        const float* wr = Wi + (size_t)(g * HID + j) * ND;
        for (int o = 0; o < ND; ++o) s += wr[o] * bo[o];
        w[g] = s;
    }
    dst[j] = make_float4(bi[j] + bh[j] + w[0],
                         bi[HID + j] + bh[HID + j] + w[1],
                         bi[2 * HID + j] + w[2],
                         bh[2 * HID + j]);
}

__global__ __launch_bounds__(256)
void zero_u32(unsigned int* __restrict__ p, int n) {
    int i = blockIdx.x * 256 + threadIdx.x;
    if (i < n) p[i] = 0u;
}

// ================= persistent cooperative kernel =============================
// grid 256 = (bt = bid&15, jq = bid>>4); 384 thr = 6 waves: (g = wv>>1, jh = wv&1)
__global__ __launch_bounds__(384, 2)
void seq_coop(const u16* __restrict__ encB, const u16* __restrict__ decB,
              const u16* __restrict__ WcB,  const u16* __restrict__ WpB,
              const u16* __restrict__ WoB,  const u16* __restrict__ xAe,
              u16* __restrict__ hA0, u16* __restrict__ hA1,
              u16* __restrict__ projA,
              const float4* __restrict__ biasE, const float4* __restrict__ biasD0,
              const float4* __restrict__ biasD1,
              const float* __restrict__ bp, const float* __restrict__ bo,
              float* __restrict__ d_out,
              unsigned int* __restrict__ syncb)
{
    const int tid  = threadIdx.x;
    const int lane = tid & 63;
    const int wv   = tid >> 6;
    const int bid  = blockIdx.x;
    const int bt   = bid & 15;
    const int jq   = bid >> 4;
    const int g    = wv >> 1;
    const int jh   = wv & 1;
    const int jf16 = jq * 2 + jh;

    unsigned int* cnt  = syncb + bt * 256;
    unsigned int* cnt2 = syncb + bt * 256 + 128;

    __shared__ u16   hstage[16 * 2 * 64 * 8];   // 32 KB: hA[bt] for this step
    __shared__ float gx[4][16][36];             // gate exchange r,z,nh,nx
    __shared__ float hprev[16][36];             // persistent h (this WG's 32 cols)

    for (int e = tid; e < 16 * 36; e += 384) (&hprev[0][0])[e] = 0.f;

    // persistent h-part weights: 16 kb x {hi,lo}
    s16x8 wH0[16], wH1[16];
    #pragma unroll
    for (int kb = 0; kb < 16; ++kb) {
        size_t b0 = ((((size_t)jf16 * 20 + kb) * 3 + g) * 2) * 512 + (size_t)lane * 8;
        wH0[kb] = *(const s16x8*)(encB + b0);
        wH1[kb] = *(const s16x8*)(encB + b0 + 512);
    }

    for (int s = 0; s < 192; ++s) {
        if (s == 128) {
            #pragma unroll
            for (int kb = 0; kb < 16; ++kb) {
                size_t b0 = ((((size_t)jf16 * 20 + kb) * 3 + g) * 2) * 512 + (size_t)lane * 8;
                wH0[kb] = *(const s16x8*)(decB + b0);
                wH1[kb] = *(const s16x8*)(decB + b0 + 512);
            }
        }
        const u16* hin  = (s & 1) ? hA1 : hA0;
        u16*       hout = (s & 1) ? hA0 : hA1;

        // ---- start-of-step wait: h(s) frags published ----
        if (s > 0) {
            if (tid == 0) {
                unsigned int tc = 16u * (unsigned)s;
                while (syncload(cnt) < tc) __builtin_amdgcn_s_sleep(1);
            }
            __syncthreads();
        }

        // ---- stage h A-frags (32 KB) into LDS via coherent loads ----
        {
            const u64* src = (const u64*)hin + (size_t)bt * 4096;
            u64* dstl = (u64*)hstage;
            #pragma unroll
            for (int i = 0; i < 10; ++i) {
                int idx = tid + i * 384;
                dstl[idx] = ld8(src + idx);
            }
            if (tid < 256) {
                int idx = tid + 3840;
                dstl[idx] = ld8(src + idx);
            }
        }
        __syncthreads();

        f32x4 a0 = fz(), a1 = fz(), a2 = fz();
        f32x4 x0 = fz(), x1 = fz(), x2 = fz();

        // ---- h part: K 0..511 from LDS, weights from VGPR ----
        #pragma unroll
        for (int kb = 0; kb < 16; ++kb) {
            s16x8 ahi = *(const s16x8*)&hstage[(size_t)kb * 1024 + lane * 8];
            s16x8 alo = *(const s16x8*)&hstage[(size_t)kb * 1024 + 512 + lane * 8];
            a0 = mfma16(ahi, wH0[kb], a0);
            a1 = mfma16(ahi, wH1[kb], a1);
            a2 = mfma16(alo, wH0[kb], a2);
        }

        // ---- x part ----
        if (s <= 128) {
            int t = (s < 128) ? s : (TIN - 1);
            const u16* wsrc = (s < 128) ? encB : decB;
            const u16* xa = xAe + (size_t)(t * 16 + bt) * 4096;
            #pragma unroll
            for (int kb = 0; kb < 4; ++kb) {
                s16x8 ahi = *(const s16x8*)(xa + (size_t)kb * 1024 + lane * 8);
                s16x8 alo = *(const s16x8*)(xa + (size_t)kb * 1024 + 512 + lane * 8);
                size_t wb = ((((size_t)jf16 * 20 + 16 + kb) * 3 + g) * 2) * 512 + (size_t)lane * 8;
                s16x8 bhi = *(const s16x8*)(wsrc + wb);
                s16x8 blo = *(const s16x8*)(wsrc + wb + 512);
                if (g == 2) { x0 = mfma16(ahi, bhi, x0); x1 = mfma16(ahi, blo, x1); x2 = mfma16(alo, bhi, x2); }
                else        { a0 = mfma16(ahi, bhi, a0); a1 = mfma16(ahi, blo, a1); a2 = mfma16(alo, bhi, a2); }
            }
        } else {
            // wait for proj(t-1) only now — overlapped the h-part above
            if (tid == 0) {
                unsigned int t2 = 8u * (unsigned)(s - 128);
                while (syncload(cnt2) < t2) __builtin_amdgcn_s_sleep(1);
            }
            __syncthreads();
            const u64* xa = (const u64*)projA + (size_t)((s - 129) & 1) * 32768
                          + (size_t)bt * 2048;
            #pragma unroll
            for (int kb = 0; kb < 8; ++kb) {
                u64x2 xh, xl;
                xh[0] = ld8(xa + (size_t)kb * 256 + lane * 2);
                xh[1] = ld8(xa + (size_t)kb * 256 + lane * 2 + 1);
                xl[0] = ld8(xa + (size_t)kb * 256 + 128 + lane * 2);
                xl[1] = ld8(xa + (size_t)kb * 256 + 128 + lane * 2 + 1);
                s16x8 ahi = __builtin_bit_cast(s16x8, xh);
                s16x8 alo = __builtin_bit_cast(s16x8, xl);
                size_t wb = ((((size_t)jf16 * 8 + kb) * 3 + g) * 2) * 512 + (size_t)lane * 8;
                s16x8 bhi = *(const s16x8*)(WcB + wb);
                s16x8 blo = *(const s16x8*)(WcB + wb + 512);
                if (g == 2) { x0 = mfma16(ahi, bhi, x0); x1 = mfma16(ahi, blo, x1); x2 = mfma16(alo, bhi, x2); }
                else        { a0 = mfma16(ahi, bhi, a0); a1 = mfma16(ahi, blo, a1); a2 = mfma16(alo, bhi, a2); }
            }
        }

        f32x4 am = a0 + a1 + a2;
        f32x4 xm = x0 + x1 + x2;

        #pragma unroll
        for (int i = 0; i < 4; ++i) {
            int r  = (lane >> 4) * 4 + i;
            int lc = jh * 16 + (lane & 15);
            gx[g][r][lc] = am[i];
            if (g == 2) gx[3][r][lc] = xm[i];
        }
        __syncthreads();

        // ---- gates + h update (512 elems over 384 threads) ----
        {
            const float4* b4p = (s < 128) ? biasE : ((s == 128) ? biasD0 : biasD1);
            for (int e = tid; e < 512; e += 384) {
                int r = e >> 5, lc = e & 31;
                float4 b4 = b4p[jq * 32 + lc];
                float rg = 1.f / (1.f + expf(-(gx[0][r][lc] + b4.x)));
                float zg = 1.f / (1.f + expf(-(gx[1][r][lc] + b4.y)));
                float ng = tanhf(gx[3][r][lc] + b4.z + rg * (gx[2][r][lc] + b4.w));
                float hv = (1.f - zg) * ng + zg * hprev[r][lc];
                hprev[r][lc] = hv;
                gx[0][r][lc] = hv;
            }
        }
        __syncthreads();

        // wave0: emit this WG's 32 h-cols as A-frags (kb = jq) for next step
        if (wv == 0) {
            s16x8 vh, vl;
            #pragma unroll
            for (int i = 0; i < 8; ++i) {
                float v = gx[0][lane & 15][(lane >> 4) * 8 + i];
                u16 hi = f2bf(v);
                vh[i] = (short)hi;
                vl[i] = (short)f2bf(v - bf2f(hi));
            }
            u64* dh = (u64*)hout + ((size_t)(bt * 16 + jq) * 2) * 128 + (size_t)lane * 2;
            u64x2 a = __builtin_bit_cast(u64x2, vh);
            u64x2 b = __builtin_bit_cast(u64x2, vl);
            st8(dh, a[0]);       st8(dh + 1, a[1]);
            st8(dh + 128, b[0]); st8(dh + 129, b[1]);
        }
        __syncthreads();                    // drains vmcnt before barrier
        if (tid == 0) syncadd(cnt);         // publish h(s+1)

        // ---- decoder: proj phase (+ piggybacked out[t-1]) ----
        if (s >= 128) {
            int t = s - 128, par = t & 1;
            // mid-phase wait
            if (tid == 0) {
                if (jq < 8) {
                    unsigned int tc = 16u * (unsigned)(s + 1);
                    while (syncload(cnt) < tc) __builtin_amdgcn_s_sleep(1);
                } else if (t >= 1) {
                    unsigned int t2 = 8u * (unsigned)t;
                    while (syncload(cnt2) < t2) __builtin_amdgcn_s_sleep(1);
                }
            }
            __syncthreads();

            if (jq < 8) {
                if (wv < 2) {
                    int pf16 = jq * 2 + wv;
                    f32x4 p0 = fz(), p1 = fz(), p2 = fz();
                    const u64* ha = (const u64*)hout + (size_t)bt * 4096;
                    const u16* wb = WpB + (size_t)pf16 * 16384;
                    #pragma unroll
                    for (int kb = 0; kb < 16; ++kb) {
                        u64x2 xh, xl;
                        xh[0] = ld8(ha + (size_t)kb * 256 + lane * 2);
                        xh[1] = ld8(ha + (size_t)kb * 256 + lane * 2 + 1);
                        xl[0] = ld8(ha + (size_t)kb * 256 + 128 + lane * 2);
                        xl[1] = ld8(ha + (size_t)kb * 256 + 128 + lane * 2 + 1);
                        s16x8 ahi = __builtin_bit_cast(s16x8, xh);
                        s16x8 alo = __builtin_bit_cast(s16x8, xl);
                        s16x8 bhi = *(const s16x8*)(wb + (size_t)kb * 1024 + lane * 8);
                        s16x8 blo = *(const s16x8*)(wb + (size_t)kb * 1024 + 512 + lane * 8);
                        p0 = mfma16(ahi, bhi, p0);
                        p1 = mfma16(ahi, blo, p1);
                        p2 = mfma16(alo, bhi, p2);
                    }
                    f32x4 pm = p0 + p1 + p2;
                    float bpv = bp[pf16 * 16 + (lane & 15)];
                    #pragma unroll
                    for (int i = 0; i < 4; ++i)
                        gx[0][(lane >> 4) * 4 + i][wv * 16 + (lane & 15)] = fmaxf(pm[i] + bpv, 0.f);
                }
            } else if (t >= 1 && wv == 0) {
                int of16 = jq - 8;
                f32x4 q0 = fz(), q1 = fz(), q2 = fz();
                const u64* pa = (const u64*)projA + (size_t)((t - 1) & 1) * 32768
                              + (size_t)bt * 2048;
                const u16* wb = WoB + (size_t)of16 * 8192;
                #pragma unroll
                for (int kb = 0; kb < 8; ++kb) {
                    u64x2 xh, xl;
                    xh[0] = ld8(pa + (size_t)kb * 256 + lane * 2);
                    xh[1] = ld8(pa + (size_t)kb * 256 + lane * 2 + 1);
                    xl[0] = ld8(pa + (size_t)kb * 256 + 128 + lane * 2);
                    xl[1] = ld8(pa + (size_t)kb * 256 + 128 + lane * 2 + 1);
                    s16x8 ahi = __builtin_bit_cast(s16x8, xh);
                    s16x8 alo = __builtin_bit_cast(s16x8, xl);
                    s16x8 bhi = *(const s16x8*)(wb + (size_t)kb * 1024 + lane * 8);
                    s16x8 blo = *(const s16x8*)(wb + (size_t)kb * 1024 + 512 + lane * 8);
                    q0 = mfma16(ahi, bhi, q0);
                    q1 = mfma16(ahi, blo, q1);
                    q2 = mfma16(alo, bhi, q2);
                }
                f32x4 qm = q0 + q1 + q2;
                float bov = bo[of16 * 16 + (lane & 15)];
                #pragma unroll
                for (int i = 0; i < 4; ++i) {
                    int b = bt * 16 + (lane >> 4) * 4 + i;
                    d_out[(size_t)b * (TOUT * ND) + (size_t)(t - 1) * ND + of16 * 16 + (lane & 15)] = qm[i] + bov;
                }
            }
            __syncthreads();
            if (jq < 8 && wv == 2) {
                s16x8 vh, vl;
                #pragma unroll
                for (int i = 0; i < 8; ++i) {
                    float v = gx[0][lane & 15][(lane >> 4) * 8 + i];
                    u16 hi = f2bf(v);
                    vh[i] = (short)hi;
                    vl[i] = (short)f2bf(v - bf2f(hi));
                }
                u64* dp = (u64*)projA + (size_t)par * 32768 + (size_t)bt * 2048
                        + (size_t)jq * 256 + (size_t)lane * 2;
                u64x2 a = __builtin_bit_cast(u64x2, vh);
                u64x2 b = __builtin_bit_cast(u64x2, vl);
                st8(dp, a[0]);       st8(dp + 1, a[1]);
                st8(dp + 128, b[0]); st8(dp + 129, b[1]);
            }
            __syncthreads();                // drains projA stores
            if (jq < 8 && tid == 0) syncadd(cnt2);   // publish proj(t)
        }
    }

    // tail: out[63] reads proj(63) (parity 1)
    if (jq >= 8) {
        if (tid == 0)
            while (syncload(cnt2) < 8u * (unsigned)TOUT) __builtin_amdgcn_s_sleep(1);
        __syncthreads();
        if (wv == 0) {
            int of16 = jq - 8;
            f32x4 q0 = fz(), q1 = fz(), q2 = fz();
            const u64* pa = (const u64*)projA + (size_t)32768 + (size_t)bt * 2048;
            const u16* wb = WoB + (size_t)of16 * 8192;
            #pragma unroll
            for (int kb = 0; kb < 8; ++kb) {
                u64x2 xh, xl;
                xh[0] = ld8(pa + (size_t)kb * 256 + lane * 2);
                xh[1] = ld8(pa + (size_t)kb * 256 + lane * 2 + 1);
                xl[0] = ld8(pa + (size_t)kb * 256 + 128 + lane * 2);
                xl[1] = ld8(pa + (size_t)kb * 256 + 128 + lane * 2 + 1);
                s16x8 ahi = __builtin_bit_cast(s16x8, xh);
                s16x8 alo = __builtin_bit_cast(s16x8, xl);
                s16x8 bhi = *(const s16x8*)(wb + (size_t)kb * 1024 + lane * 8);
                s16x8 blo = *(const s16x8*)(wb + (size_t)kb * 1024 + 512 + lane * 8);
                q0 = mfma16(ahi, bhi, q0);
                q1 = mfma16(ahi, blo, q1);
                q2 = mfma16(alo, bhi, q2);
            }
            f32x4 qm = q0 + q1 + q2;
            float bov = bo[of16 * 16 + (lane & 15)];
            #pragma unroll
            for (int i = 0; i < 4; ++i) {
                int b = bt * 16 + (lane >> 4) * 4 + i;
                d_out[(size_t)b * (TOUT * ND) + (size_t)63 * ND + of16 * 16 + (lane & 15)] = qm[i] + bov;
            }
        }
    }
}

// ================= host =================
extern "C" void kernel_launch(void* const* d_in, const int* in_sizes, int n_in,
                              void* d_out, int out_size, void* d_ws, size_t ws_size,
                              hipStream_t stream)
{
    (void)in_sizes; (void)n_in; (void)out_size; (void)ws_size;

    const float* X      = (const float*)d_in[0];
    const float* enc_Wi = (const float*)d_in[1];
    const float* enc_Wh = (const float*)d_in[2];
    const float* enc_bi = (const float*)d_in[3];
    const float* enc_bh = (const float*)d_in[4];
    const float* dec_Wi = (const float*)d_in[5];
    const float* dec_Wh = (const float*)d_in[6];
    const float* dec_bi = (const float*)d_in[7];
    const float* dec_bh = (const float*)d_in[8];
    const float* Wp     = (const float*)d_in[9];
    const float* bp     = (const float*)d_in[10];
    const float* Wo     = (const float*)d_in[11];
    const float* bo     = (const float*)d_in[12];
    float* outp = (float*)d_out;

    char* w = (char*)d_ws;
    size_t off = 0;
    auto alloc = [&](size_t bytes) { void* p = w + off; off += (bytes + 255) & ~(size_t)255; return p; };

    u16* encB  = (u16*)alloc((size_t)32 * 20 * 3 * 2 * 512 * 2);   // 3.93 MB
    u16* decB  = (u16*)alloc((size_t)32 * 20 * 3 * 2 * 512 * 2);   // 3.93 MB
    u16* WcB   = (u16*)alloc((size_t)32 * 8 * 3 * 2 * 512 * 2);    // 1.57 MB
    u16* WpB   = (u16*)alloc((size_t)16 * 16 * 2 * 512 * 2);       // 0.5 MB
    u16* WoB   = (u16*)alloc((size_t)8 * 8 * 2 * 512 * 2);         // 128 KB
    u16* xAe   = (u16*)alloc((size_t)TIN * 16 * 4 * 2 * 512 * 2);  // 16.8 MB
    u16* hA0   = (u16*)alloc((size_t)16 * 16 * 2 * 512 * 2);       // 512 KB
    u16* hA1   = (u16*)alloc((size_t)16 * 16 * 2 * 512 * 2);
    u16* projA = (u16*)alloc((size_t)2 * 16 * 8 * 2 * 512 * 2);    // 512 KB
    float4* biasE  = (float4*)alloc(HID * 16);
    float4* biasD0 = (float4*)alloc(HID * 16);
    float4* biasD1 = (float4*)alloc(HID * 16);
    unsigned int* syncb = (unsigned int*)alloc(16 * 256 * 4);      // 16 KB

    // prep (parallel, every call — deterministic)
    zero_u32<<<16, 256, 0, stream>>>(syncb, 16 * 256);
    zero_u32<<<512, 256, 0, stream>>>((unsigned int*)hA0, 16 * 16 * 2 * 512 / 2);
    pack_gru_w<<<480, 256, 0, stream>>>(enc_Wh, enc_Wi, encB);
    pack_gru_w<<<480, 256, 0, stream>>>(dec_Wh, dec_Wi, decB);
    pack_wc<<<192, 256, 0, stream>>>(dec_Wi, Wo, WcB);
    pack_plain_w<<<64, 256, 0, stream>>>(Wp, HID, 16, 16, WpB);
    pack_plain_w<<<16, 256, 0, stream>>>(Wo, PROJD, 8, 8, WoB);
    pack_xa<<<2048, 256, 0, stream>>>(X, xAe);
    prep_bias<<<2, 256, 0, stream>>>(enc_bi, enc_bh, biasE);
    prep_bias<<<2, 256, 0, stream>>>(dec_bi, dec_bh, biasD0);
    prep_bias2<<<2, 256, 0, stream>>>(dec_bi, dec_bh, dec_Wi, bo, biasD1);

    void* args[] = { &encB, &decB, &WcB, &WpB, &WoB, &xAe, &hA0, &hA1, &projA,
                     &biasE, &biasD0, &biasD1, (void*)&bp, (void*)&bo, &outp,
                     &syncb };
    hipLaunchCooperativeKernel((void*)seq_coop, dim3(NWG), dim3(384), args, 0, stream);
}

// Round 6
// 1882.065 us; speedup vs baseline: 3.3650x; 1.0056x over previous
//
#include <hip/hip_runtime.h>
#include <math.h>

#define TIN   128
#define TOUT  64
#define ND    128
#define HID   512
#define PROJD 256
#define BSZ   256
#define NWG   256

using f32x4 = __attribute__((ext_vector_type(4))) float;
using s16x8 = __attribute__((ext_vector_type(8))) short;
using i32x4 = __attribute__((ext_vector_type(4))) int;
typedef unsigned short u16;

__device__ __forceinline__ u16 f2bf(float x) {
    unsigned int u = __builtin_bit_cast(unsigned int, x);
    u += 0x7fffu + ((u >> 16) & 1u);          // RNE (finite values)
    return (u16)(u >> 16);
}
__device__ __forceinline__ float bf2f(u16 b) {
    unsigned int u = ((unsigned int)b) << 16;
    return __builtin_bit_cast(float, u);
}
__device__ __forceinline__ f32x4 mfma16(s16x8 a, s16x8 b, f32x4 c) {
    return __builtin_amdgcn_mfma_f32_16x16x32_bf16(a, b, c, 0, 0, 0);
}
__device__ __forceinline__ f32x4 fz() { return (f32x4){0.f, 0.f, 0.f, 0.f}; }

// ---- batched LLC-coherent (L1/L2-bypass) data movement ----
__device__ __forceinline__ i32x4 ld16(const void* p) {
    i32x4 r;
    asm volatile("global_load_dwordx4 %0, %1, off sc0 sc1" : "=v"(r) : "v"(p) : "memory");
    return r;
}
__device__ __forceinline__ void st16(void* p, i32x4 v) {
    asm volatile("global_store_dwordx4 %0, %1, off sc0 sc1" :: "v"(p), "v"(v) : "memory");
}
__device__ __forceinline__ void vm_drain() {
    asm volatile("s_waitcnt vmcnt(0)" ::: "memory");
    __builtin_amdgcn_sched_barrier(0);
}
// flags stay relaxed atomics (one per phase, not on the data path)
__device__ __forceinline__ unsigned int syncload(const unsigned int* p) {
    return __hip_atomic_load(p, __ATOMIC_RELAXED, __HIP_MEMORY_SCOPE_AGENT);
}
__device__ __forceinline__ void syncadd(unsigned int* p) {
    __hip_atomic_fetch_add(p, 1u, __ATOMIC_RELAXED, __HIP_MEMORY_SCOPE_AGENT);
}
__device__ __forceinline__ void pollwave(const unsigned int* p, unsigned int tgt) {
    while (syncload(p) < tgt) __builtin_amdgcn_s_sleep(1);
}

// stage 32 KB global -> LDS, 384 threads, one vmcnt drain
__device__ __forceinline__ void stage32k(const char* src, char* dst, int tid) {
    const char* a = src + (size_t)tid * 16;
    char* d = dst + tid * 16;
    i32x4 r0 = ld16(a);
    i32x4 r1 = ld16(a + 6144);
    i32x4 r2 = ld16(a + 12288);
    i32x4 r3 = ld16(a + 18432);
    i32x4 r4 = ld16(a + 24576);
    i32x4 r5 = {0, 0, 0, 0};
    bool gg = tid < 128;
    if (gg) r5 = ld16(a + 30720);
    vm_drain();
    *(i32x4*)d = r0;
    *(i32x4*)(d + 6144) = r1;
    *(i32x4*)(d + 12288) = r2;
    *(i32x4*)(d + 18432) = r3;
    *(i32x4*)(d + 24576) = r4;
    if (gg) *(i32x4*)(d + 30720) = r5;
}
// stage 16 KB global -> LDS
__device__ __forceinline__ void stage16k(const char* src, char* dst, int tid) {
    const char* a = src + (size_t)tid * 16;
    char* d = dst + tid * 16;
    i32x4 r0 = ld16(a);
    i32x4 r1 = ld16(a + 6144);
    i32x4 r2 = {0, 0, 0, 0};
    bool gg = tid < 256;
    if (gg) r2 = ld16(a + 12288);
    vm_drain();
    *(i32x4*)d = r0;
    *(i32x4*)(d + 6144) = r1;
    if (gg) *(i32x4*)(d + 12288) = r2;
}

// ================= prep kernels (parallel, off critical path) =================

// GRU weights: [jf16(32)][kb(20: 0-15 Wh,16-19 Wi)][g(3)][hl(2)][64][8]
__global__ __launch_bounds__(256)
void pack_gru_w(const float* __restrict__ Wh, const float* __restrict__ Wi,
                u16* __restrict__ dst)
{
    int idx  = blockIdx.x * 256 + threadIdx.x;       // 32*20*3*64 = 122880
    int lane = idx & 63;
    int t    = idx >> 6;
    int g    = t % 3;  t /= 3;
    int kb   = t % 20; t /= 20;
    int jf16 = t;
    if (jf16 >= 32) return;
    int row = g * HID + jf16 * 16 + (lane & 15);
    int kk  = kb * 32 + (lane >> 4) * 8;
    float v[8];
    if (kb < 16) { const float* s = Wh + (size_t)row * HID + kk;
        #pragma unroll
        for (int i = 0; i < 8; ++i) v[i] = s[i];
    } else { const float* s = Wi + (size_t)row * ND + (kk - HID);
        #pragma unroll
        for (int i = 0; i < 8; ++i) v[i] = s[i];
    }
    size_t base = ((((size_t)(jf16 * 20 + kb) * 3 + g) * 2) * 64 + lane) * 8;
    #pragma unroll
    for (int i = 0; i < 8; ++i) {
        u16 hi = f2bf(v[i]);
        dst[base + i]       = hi;
        dst[base + 512 + i] = f2bf(v[i] - bf2f(hi));
    }
}

// Wc = dec_Wi @ Wo  [1536][256] -> frags [jf16(32)][kb(8)][g(3)][hl][64][8]
__global__ __launch_bounds__(256)
void pack_wc(const float* __restrict__ Wi, const float* __restrict__ Wo,
             u16* __restrict__ dst)
{
    int idx  = blockIdx.x * 256 + threadIdx.x;       // 32*8*3*64 = 49152
    int lane = idx & 63;
    int t    = idx >> 6;
    int g    = t % 3; t /= 3;
    int kb   = t % 8; t /= 8;
    int jf16 = t;
    if (jf16 >= 32) return;
    int row = g * HID + jf16 * 16 + (lane & 15);
    int p0  = kb * 32 + (lane >> 4) * 8;
    float acc[8] = {0.f,0.f,0.f,0.f,0.f,0.f,0.f,0.f};
    for (int o = 0; o < ND; ++o) {
        float wi = Wi[(size_t)row * ND + o];
        const float* wo = Wo + (size_t)o * PROJD + p0;
        #pragma unroll
        for (int i = 0; i < 8; ++i) acc[i] += wi * wo[i];
    }
    size_t base = ((((size_t)(jf16 * 8 + kb) * 3 + g) * 2) * 64 + lane) * 8;
    #pragma unroll
    for (int i = 0; i < 8; ++i) {
        u16 hi = f2bf(acc[i]);
        dst[base + i]       = hi;
        dst[base + 512 + i] = f2bf(acc[i] - bf2f(hi));
    }
}

// plain weight (no gates): [jf16][kb][hl][64][8]
__global__ __launch_bounds__(256)
void pack_plain_w(const float* __restrict__ W, int K, int NF, int KB,
                  u16* __restrict__ dst)
{
    int idx  = blockIdx.x * 256 + threadIdx.x;
    int lane = idx & 63;
    int t    = idx >> 6;
    int kb   = t % KB;
    int jf16 = t / KB;
    if (jf16 >= NF) return;
    int row = jf16 * 16 + (lane & 15);
    int kk  = kb * 32 + (lane >> 4) * 8;
    const float* s = W + (size_t)row * K + kk;
    size_t base = (((size_t)(jf16 * KB + kb) * 2) * 64 + lane) * 8;
    #pragma unroll
    for (int i = 0; i < 8; ++i) {
        float v = s[i];
        u16 hi = f2bf(v);
        dst[base + i]       = hi;
        dst[base + 512 + i] = f2bf(v - bf2f(hi));
    }
}

// X -> A-frags for every encoder step: [t(128)][bt(16)][kb(4)][hl][64][8]
__global__ __launch_bounds__(256)
void pack_xa(const float* __restrict__ X, u16* __restrict__ dst)
{
    int idx  = blockIdx.x * 256 + threadIdx.x;       // 128*16*4*64 = 524288
    int lane = idx & 63;
    int t2   = idx >> 6;
    int kb   = t2 & 3;  t2 >>= 2;
    int bt   = t2 & 15; t2 >>= 4;
    int t    = t2;
    if (t >= TIN) return;
    int b = bt * 16 + (lane & 15);
    int d = kb * 32 + (lane >> 4) * 8;
    const float* s = X + (size_t)b * TIN * ND + (size_t)t * ND + d;
    size_t base = ((((size_t)(t * 16 + bt) * 4 + kb) * 2) * 64 + lane) * 8;
    #pragma unroll
    for (int i = 0; i < 8; ++i) {
        float v = s[i];
        u16 hi = f2bf(v);
        dst[base + i]       = hi;
        dst[base + 512 + i] = f2bf(v - bf2f(hi));
    }
}

__global__ __launch_bounds__(256)
void prep_bias(const float* __restrict__ bi, const float* __restrict__ bh,
               float4* __restrict__ dst)
{
    int j = blockIdx.x * 256 + threadIdx.x;
    if (j >= HID) return;
    dst[j] = make_float4(bi[j] + bh[j],
                         bi[HID + j] + bh[HID + j],
                         bi[2 * HID + j],
                         bh[2 * HID + j]);
}

// decoder steps>=1: x-bias folded with Wi@bo
__global__ __launch_bounds__(256)
void prep_bias2(const float* __restrict__ bi, const float* __restrict__ bh,
                const float* __restrict__ Wi, const float* __restrict__ bo,
                float4* __restrict__ dst)
{
    int j = blockIdx.x * 256 + threadIdx.x;
    if (j >= HID) return;
    float w[3];
    #pragma unroll
    for (int g = 0; g < 3; ++g) {
        float s = 0.f;
        const float* wr = Wi + (size_t)(g * HID + j) * ND;
        for (int o = 0; o < ND; ++o) s += wr[o] * bo[o];
        w[g] = s;
    }
    dst[j] = make_float4(bi[j] + bh[j] + w[0],
                         bi[HID + j] + bh[HID + j] + w[1],
                         bi[2 * HID + j] + w[2],
                         bh[2 * HID + j]);
}

__global__ __launch_bounds__(256)
void zero_u32(unsigned int* __restrict__ p, int n) {
    int i = blockIdx.x * 256 + threadIdx.x;
    if (i < n) p[i] = 0u;
}

// ================= persistent cooperative kernel =============================
// grid 256 = (bt = bid&15, jq = bid>>4); 384 thr = 6 waves: (g = wv>>1, jh = wv&1)
__global__ __launch_bounds__(384, 1)
void seq_coop(const u16* __restrict__ encB, const u16* __restrict__ decB,
              const u16* __restrict__ WcB,  const u16* __restrict__ WpB,
              const u16* __restrict__ WoB,  const u16* __restrict__ xAe,
              u16* __restrict__ hA0, u16* __restrict__ hA1,
              u16* __restrict__ projA,
              const float4* __restrict__ biasE, const float4* __restrict__ biasD0,
              const float4* __restrict__ biasD1,
              const float* __restrict__ bp, const float* __restrict__ bo,
              float* __restrict__ d_out,
              unsigned int* __restrict__ syncb)
{
    const int tid  = threadIdx.x;
    const int lane = tid & 63;
    const int wv   = tid >> 6;
    const int bid  = blockIdx.x;
    const int bt   = bid & 15;
    const int jq   = bid >> 4;
    const int g    = wv >> 1;
    const int jh   = wv & 1;
    const int jf16 = jq * 2 + jh;

    unsigned int* cnt  = syncb + bt * 256;
    unsigned int* cnt2 = syncb + bt * 256 + 128;

    __shared__ __align__(16) u16 hstage[16384];   // 32 KB: hA[bt] for this step
    __shared__ __align__(16) u16 pstage[8192];    // 16 KB: projA[par][bt] (x-part)
    __shared__ __align__(16) u16 ostage[8192];    // 16 KB: projA (out-phase)
    __shared__ float gx[4][16][36];               // gate exchange r,z,nh,nx
    __shared__ float hprev[16][36];               // persistent h (this WG's 32 cols)

    for (int e = tid; e < 16 * 36; e += 384) (&hprev[0][0])[e] = 0.f;

    // persistent h-part weights: 16 kb x {hi,lo}
    s16x8 wH0[16], wH1[16];
    #pragma unroll
    for (int kb = 0; kb < 16; ++kb) {
        size_t b0 = ((((size_t)jf16 * 20 + kb) * 3 + g) * 2) * 512 + (size_t)lane * 8;
        wH0[kb] = *(const s16x8*)(encB + b0);
        wH1[kb] = *(const s16x8*)(encB + b0 + 512);
    }

    for (int s = 0; s < 192; ++s) {
        if (s == 128) {
            #pragma unroll
            for (int kb = 0; kb < 16; ++kb) {
                size_t b0 = ((((size_t)jf16 * 20 + kb) * 3 + g) * 2) * 512 + (size_t)lane * 8;
                wH0[kb] = *(const s16x8*)(decB + b0);
                wH1[kb] = *(const s16x8*)(decB + b0 + 512);
            }
        }
        const u16* hin  = (s & 1) ? hA1 : hA0;
        u16*       hout = (s & 1) ? hA0 : hA1;

        // hoist encoder x-frag loads (independent of h) so they fly during the wait
        s16x8 xh[4], xl[4];
        if (s <= 128) {
            int t = (s < 128) ? s : (TIN - 1);
            const u16* xa = xAe + (size_t)(t * 16 + bt) * 4096;
            #pragma unroll
            for (int kb = 0; kb < 4; ++kb) {
                xh[kb] = *(const s16x8*)(xa + (size_t)kb * 1024 + lane * 8);
                xl[kb] = *(const s16x8*)(xa + (size_t)kb * 1024 + 512 + lane * 8);
            }
        }

        // ---- wait for h(s), stage into LDS (per-wave poll, batched burst) ----
        if (s > 0) pollwave(cnt, 16u * (unsigned)s);
        stage32k((const char*)hin + (size_t)bt * 32768, (char*)hstage, tid);
        __syncthreads();

        f32x4 a0 = fz(), a1 = fz(), a2 = fz();
        f32x4 x0 = fz(), x1 = fz(), x2 = fz();

        // ---- h part: K 0..511 from LDS, weights from VGPR ----
        #pragma unroll
        for (int kb = 0; kb < 16; ++kb) {
            s16x8 ahi = *(const s16x8*)&hstage[(size_t)kb * 1024 + lane * 8];
            s16x8 alo = *(const s16x8*)&hstage[(size_t)kb * 1024 + 512 + lane * 8];
            a0 = mfma16(ahi, wH0[kb], a0);
            a1 = mfma16(ahi, wH1[kb], a1);
            a2 = mfma16(alo, wH0[kb], a2);
        }

        // ---- x part ----
        if (s <= 128) {
            const u16* wsrc = (s < 128) ? encB : decB;
            #pragma unroll
            for (int kb = 0; kb < 4; ++kb) {
                size_t wb = ((((size_t)jf16 * 20 + 16 + kb) * 3 + g) * 2) * 512 + (size_t)lane * 8;
                s16x8 bhi = *(const s16x8*)(wsrc + wb);
                s16x8 blo = *(const s16x8*)(wsrc + wb + 512);
                if (g == 2) { x0 = mfma16(xh[kb], bhi, x0); x1 = mfma16(xh[kb], blo, x1); x2 = mfma16(xl[kb], bhi, x2); }
                else        { a0 = mfma16(xh[kb], bhi, a0); a1 = mfma16(xh[kb], blo, a1); a2 = mfma16(xl[kb], bhi, a2); }
            }
        } else {
            pollwave(cnt2, 8u * (unsigned)(s - 128));   // proj(t-1) ready
            stage16k((const char*)projA + (size_t)((s - 129) & 1) * 262144
                     + (size_t)bt * 16384, (char*)pstage, tid);
            __syncthreads();
            #pragma unroll
            for (int kb = 0; kb < 8; ++kb) {
                s16x8 ahi = *(const s16x8*)&pstage[(size_t)kb * 1024 + lane * 8];
                s16x8 alo = *(const s16x8*)&pstage[(size_t)kb * 1024 + 512 + lane * 8];
                size_t wb = ((((size_t)jf16 * 8 + kb) * 3 + g) * 2) * 512 + (size_t)lane * 8;
                s16x8 bhi = *(const s16x8*)(WcB + wb);
                s16x8 blo = *(const s16x8*)(WcB + wb + 512);
                if (g == 2) { x0 = mfma16(ahi, bhi, x0); x1 = mfma16(ahi, blo, x1); x2 = mfma16(alo, bhi, x2); }
                else        { a0 = mfma16(ahi, bhi, a0); a1 = mfma16(ahi, blo, a1); a2 = mfma16(alo, bhi, a2); }
            }
        }

        f32x4 am = a0 + a1 + a2;
        f32x4 xm = x0 + x1 + x2;

        #pragma unroll
        for (int i = 0; i < 4; ++i) {
            int r  = (lane >> 4) * 4 + i;
            int lc = jh * 16 + (lane & 15);
            gx[g][r][lc] = am[i];
            if (g == 2) gx[3][r][lc] = xm[i];
        }
        __syncthreads();

        // ---- gates + h update (512 elems over 384 threads) ----
        {
            const float4* b4p = (s < 128) ? biasE : ((s == 128) ? biasD0 : biasD1);
            for (int e = tid; e < 512; e += 384) {
                int r = e >> 5, lc = e & 31;
                float4 b4 = b4p[jq * 32 + lc];
                float rg = 1.f / (1.f + expf(-(gx[0][r][lc] + b4.x)));
                float zg = 1.f / (1.f + expf(-(gx[1][r][lc] + b4.y)));
                float ng = tanhf(gx[3][r][lc] + b4.z + rg * (gx[2][r][lc] + b4.w));
                float hv = (1.f - zg) * ng + zg * hprev[r][lc];
                hprev[r][lc] = hv;
                gx[0][r][lc] = hv;
            }
        }
        __syncthreads();

        // wave0: emit this WG's 32 h-cols as A-frags (chunk kb = jq) for next step
        if (wv == 0) {
            s16x8 vh, vl;
            #pragma unroll
            for (int i = 0; i < 8; ++i) {
                float v = gx[0][lane & 15][(lane >> 4) * 8 + i];
                u16 hi = f2bf(v);
                vh[i] = (short)hi;
                vl[i] = (short)f2bf(v - bf2f(hi));
            }
            char* dh = (char*)hout + (size_t)(bt * 16 + jq) * 2048 + (size_t)lane * 16;
            st16(dh,        __builtin_bit_cast(i32x4, vh));
            st16(dh + 1024, __builtin_bit_cast(i32x4, vl));
            vm_drain();                       // wave-level: covers all 64 lanes' stores
            if (tid == 0) syncadd(cnt);       // publish h(s+1)
        }

        // ---- decoder: proj phase / out phase ----
        if (s >= 128) {
            int t = s - 128, par = t & 1;
            if (jq < 8) {
                pollwave(cnt, 16u * (unsigned)(s + 1));     // h(s+1) fully published
                stage32k((const char*)hout + (size_t)bt * 32768, (char*)hstage, tid);
                __syncthreads();
                if (wv < 2) {
                    int pf16 = jq * 2 + wv;
                    f32x4 p0 = fz(), p1 = fz(), p2 = fz();
                    const u16* wb = WpB + (size_t)pf16 * 16384;
                    #pragma unroll
                    for (int kb = 0; kb < 16; ++kb) {
                        s16x8 ahi = *(const s16x8*)&hstage[(size_t)kb * 1024 + lane * 8];
                        s16x8 alo = *(const s16x8*)&hstage[(size_t)kb * 1024 + 512 + lane * 8];
                        s16x8 bhi = *(const s16x8*)(wb + (size_t)kb * 1024 + lane * 8);
                        s16x8 blo = *(const s16x8*)(wb + (size_t)kb * 1024 + 512 + lane * 8);
                        p0 = mfma16(ahi, bhi, p0);
                        p1 = mfma16(ahi, blo, p1);
                        p2 = mfma16(alo, bhi, p2);
                    }
                    f32x4 pm = p0 + p1 + p2;
                    float bpv = bp[pf16 * 16 + (lane & 15)];
                    #pragma unroll
                    for (int i = 0; i < 4; ++i)
                        gx[0][(lane >> 4) * 4 + i][wv * 16 + (lane & 15)] = fmaxf(pm[i] + bpv, 0.f);
                }
                __syncthreads();
                if (wv == 2) {
                    s16x8 vh, vl;
                    #pragma unroll
                    for (int i = 0; i < 8; ++i) {
                        float v = gx[0][lane & 15][(lane >> 4) * 8 + i];
                        u16 hi = f2bf(v);
                        vh[i] = (short)hi;
                        vl[i] = (short)f2bf(v - bf2f(hi));
                    }
                    char* dp = (char*)projA + (size_t)par * 262144 + (size_t)bt * 16384
                             + (size_t)jq * 2048 + (size_t)lane * 16;
                    st16(dp,        __builtin_bit_cast(i32x4, vh));
                    st16(dp + 1024, __builtin_bit_cast(i32x4, vl));
                    vm_drain();
                    if (tid == 128) syncadd(cnt2);          // publish proj(t)
                }
            } else if (t >= 1) {
                pollwave(cnt2, 8u * (unsigned)t);           // proj(t-1) ready
                stage16k((const char*)projA + (size_t)((t - 1) & 1) * 262144
                         + (size_t)bt * 16384, (char*)ostage, tid);
                __syncthreads();
                if (wv == 0) {
                    int of16 = jq - 8;
                    f32x4 q0 = fz(), q1 = fz(), q2 = fz();
                    const u16* wb = WoB + (size_t)of16 * 8192;
                    #pragma unroll
                    for (int kb = 0; kb < 8; ++kb) {
                        s16x8 ahi = *(const s16x8*)&ostage[(size_t)kb * 1024 + lane * 8];
                        s16x8 alo = *(const s16x8*)&ostage[(size_t)kb * 1024 + 512 + lane * 8];
                        s16x8 bhi = *(const s16x8*)(wb + (size_t)kb * 1024 + lane * 8);
                        s16x8 blo = *(const s16x8*)(wb + (size_t)kb * 1024 + 512 + lane * 8);
                        q0 = mfma16(ahi, bhi, q0);
                        q1 = mfma16(ahi, blo, q1);
                        q2 = mfma16(alo, bhi, q2);
                    }
                    f32x4 qm = q0 + q1 + q2;
                    float bov = bo[of16 * 16 + (lane & 15)];
                    #pragma unroll
                    for (int i = 0; i < 4; ++i) {
                        int b = bt * 16 + (lane >> 4) * 4 + i;
                        d_out[(size_t)b * (TOUT * ND) + (size_t)(t - 1) * ND + of16 * 16 + (lane & 15)] = qm[i] + bov;
                    }
                }
            }
        }
    }

    // tail: out[63] reads proj(63) (parity 1)
    if (jq >= 8) {
        pollwave(cnt2, 8u * (unsigned)TOUT);
        stage16k((const char*)projA + (size_t)262144 + (size_t)bt * 16384,
                 (char*)ostage, tid);
        __syncthreads();
        if (wv == 0) {
            int of16 = jq - 8;
            f32x4 q0 = fz(), q1 = fz(), q2 = fz();
            const u16* wb = WoB + (size_t)of16 * 8192;
            #pragma unroll
            for (int kb = 0; kb < 8; ++kb) {
                s16x8 ahi = *(const s16x8*)&ostage[(size_t)kb * 1024 + lane * 8];
                s16x8 alo = *(const s16x8*)&ostage[(size_t)kb * 1024 + 512 + lane * 8];
                s16x8 bhi = *(const s16x8*)(wb + (size_t)kb * 1024 + lane * 8);
                s16x8 blo = *(const s16x8*)(wb + (size_t)kb * 1024 + 512 + lane * 8);
                q0 = mfma16(ahi, bhi, q0);
                q1 = mfma16(ahi, blo, q1);
                q2 = mfma16(alo, bhi, q2);
            }
            f32x4 qm = q0 + q1 + q2;
            float bov = bo[of16 * 16 + (lane & 15)];
            #pragma unroll
            for (int i = 0; i < 4; ++i) {
                int b = bt * 16 + (lane >> 4) * 4 + i;
                d_out[(size_t)b * (TOUT * ND) + (size_t)63 * ND + of16 * 16 + (lane & 15)] = qm[i] + bov;
            }
        }
    }
}

// ================= host =================
extern "C" void kernel_launch(void* const* d_in, const int* in_sizes, int n_in,
                              void* d_out, int out_size, void* d_ws, size_t ws_size,
                              hipStream_t stream)
{
    (void)in_sizes; (void)n_in; (void)out_size; (void)ws_size;

    const float* X      = (const float*)d_in[0];
    const float* enc_Wi = (const float*)d_in[1];
    const float* enc_Wh = (const float*)d_in[2];
    const float* enc_bi = (const float*)d_in[3];
    const float* enc_bh = (const float*)d_in[4];
    const float* dec_Wi = (const float*)d_in[5];
    const float* dec_Wh = (const float*)d_in[6];
    const float* dec_bi = (const float*)d_in[7];
    const float* dec_bh = (const float*)d_in[8];
    const float* Wp     = (const float*)d_in[9];
    const float* bp     = (const float*)d_in[10];
    const float* Wo     = (const float*)d_in[11];
    const float* bo     = (const float*)d_in[12];
    float* outp = (float*)d_out;

    char* w = (char*)d_ws;
    size_t off = 0;
    auto alloc = [&](size_t bytes) { void* p = w + off; off += (bytes + 255) & ~(size_t)255; return p; };

    u16* encB  = (u16*)alloc((size_t)32 * 20 * 3 * 2 * 512 * 2);   // 3.93 MB
    u16* decB  = (u16*)alloc((size_t)32 * 20 * 3 * 2 * 512 * 2);   // 3.93 MB
    u16* WcB   = (u16*)alloc((size_t)32 * 8 * 3 * 2 * 512 * 2);    // 1.57 MB
    u16* WpB   = (u16*)alloc((size_t)16 * 16 * 2 * 512 * 2);       // 0.5 MB
    u16* WoB   = (u16*)alloc((size_t)8 * 8 * 2 * 512 * 2);         // 128 KB
    u16* xAe   = (u16*)alloc((size_t)TIN * 16 * 4 * 2 * 512 * 2);  // 16.8 MB
    u16* hA0   = (u16*)alloc((size_t)16 * 16 * 2 * 512 * 2);       // 512 KB
    u16* hA1   = (u16*)alloc((size_t)16 * 16 * 2 * 512 * 2);
    u16* projA = (u16*)alloc((size_t)2 * 16 * 8 * 2 * 512 * 2);    // 512 KB
    float4* biasE  = (float4*)alloc(HID * 16);
    float4* biasD0 = (float4*)alloc(HID * 16);
    float4* biasD1 = (float4*)alloc(HID * 16);
    unsigned int* syncb = (unsigned int*)alloc(16 * 256 * 4);      // 16 KB

    // prep (parallel, every call — deterministic)
    zero_u32<<<16, 256, 0, stream>>>(syncb, 16 * 256);
    zero_u32<<<512, 256, 0, stream>>>((unsigned int*)hA0, 16 * 16 * 2 * 512 / 2);
    pack_gru_w<<<480, 256, 0, stream>>>(enc_Wh, enc_Wi, encB);
    pack_gru_w<<<480, 256, 0, stream>>>(dec_Wh, dec_Wi, decB);
    pack_wc<<<192, 256, 0, stream>>>(dec_Wi, Wo, WcB);
    pack_plain_w<<<64, 256, 0, stream>>>(Wp, HID, 16, 16, WpB);
    pack_plain_w<<<16, 256, 0, stream>>>(Wo, PROJD, 8, 8, WoB);
    pack_xa<<<2048, 256, 0, stream>>>(X, xAe);
    prep_bias<<<2, 256, 0, stream>>>(enc_bi, enc_bh, biasE);
    prep_bias<<<2, 256, 0, stream>>>(dec_bi, dec_bh, biasD0);
    prep_bias2<<<2, 256, 0, stream>>>(dec_bi, dec_bh, dec_Wi, bo, biasD1);

    void* args[] = { &encB, &decB, &WcB, &WpB, &WoB, &xAe, &hA0, &hA1, &projA,
                     &biasE, &biasD0, &biasD1, (void*)&bp, (void*)&bo, &outp,
                     &syncb };
    hipLaunchCooperativeKernel((void*)seq_coop, dim3(NWG), dim3(384), args, 0, stream);
}

// Round 7
// 1583.265 us; speedup vs baseline: 4.0000x; 1.1887x over previous
//
#include <hip/hip_runtime.h>
#include <math.h>

#define TIN   128
#define TOUT  64
#define ND    128
#define HID   512
#define PROJD 256
#define BSZ   256
#define NWG   256

using f32x4 = __attribute__((ext_vector_type(4))) float;
using s16x8 = __attribute__((ext_vector_type(8))) short;
using i32x4 = __attribute__((ext_vector_type(4))) int;
typedef unsigned short u16;

__device__ __forceinline__ u16 f2bf(float x) {
    unsigned int u = __builtin_bit_cast(unsigned int, x);
    u += 0x7fffu + ((u >> 16) & 1u);          // RNE (finite values)
    return (u16)(u >> 16);
}
__device__ __forceinline__ float bf2f(u16 b) {
    unsigned int u = ((unsigned int)b) << 16;
    return __builtin_bit_cast(float, u);
}
__device__ __forceinline__ f32x4 mfma16(s16x8 a, s16x8 b, f32x4 c) {
    return __builtin_amdgcn_mfma_f32_16x16x32_bf16(a, b, c, 0, 0, 0);
}
__device__ __forceinline__ f32x4 fz() { return (f32x4){0.f, 0.f, 0.f, 0.f}; }

// ---- batched LLC-coherent (L1/L2-bypass) data movement ----
__device__ __forceinline__ i32x4 ld16(const void* p) {
    i32x4 r;
    asm volatile("global_load_dwordx4 %0, %1, off sc0 sc1" : "=v"(r) : "v"(p) : "memory");
    return r;
}
__device__ __forceinline__ void st16(void* p, i32x4 v) {
    asm volatile("global_store_dwordx4 %0, %1, off sc0 sc1" :: "v"(p), "v"(v) : "memory");
}
__device__ __forceinline__ void vm_drain() {
    asm volatile("s_waitcnt vmcnt(0)" ::: "memory");
    __builtin_amdgcn_sched_barrier(0);
}

// ---- tag-based handoff: one 64B line per producer, relaxed agent scope ----
#define TAGSTRIDE 16   // u32 units = 64 B
__device__ __forceinline__ unsigned int tag_load(const unsigned int* p) {
    return __hip_atomic_load(p, __ATOMIC_RELAXED, __HIP_MEMORY_SCOPE_AGENT);
}
__device__ __forceinline__ void tag_store(unsigned int* p, unsigned int v) {
    __hip_atomic_store(p, v, __ATOMIC_RELAXED, __HIP_MEMORY_SCOPE_AGENT);
}
// wave-level: lanes 0..n-1 each poll a distinct tag line until >= tgt
__device__ __forceinline__ void poll_tags(const unsigned int* base, int n,
                                          unsigned int tgt, int lane) {
    const unsigned int* p = base + (size_t)(lane < n ? lane : 0) * TAGSTRIDE;
    while (tag_load(p) < tgt) __builtin_amdgcn_s_sleep(2);
}

// stage 32 KB global -> LDS, 384 threads, one vmcnt drain
__device__ __forceinline__ void stage32k(const char* src, char* dst, int tid) {
    const char* a = src + (size_t)tid * 16;
    char* d = dst + tid * 16;
    i32x4 r0 = ld16(a);
    i32x4 r1 = ld16(a + 6144);
    i32x4 r2 = ld16(a + 12288);
    i32x4 r3 = ld16(a + 18432);
    i32x4 r4 = ld16(a + 24576);
    i32x4 r5 = {0, 0, 0, 0};
    bool gg = tid < 128;
    if (gg) r5 = ld16(a + 30720);
    vm_drain();
    *(i32x4*)d = r0;
    *(i32x4*)(d + 6144) = r1;
    *(i32x4*)(d + 12288) = r2;
    *(i32x4*)(d + 18432) = r3;
    *(i32x4*)(d + 24576) = r4;
    if (gg) *(i32x4*)(d + 30720) = r5;
}
// stage 16 KB global -> LDS
__device__ __forceinline__ void stage16k(const char* src, char* dst, int tid) {
    const char* a = src + (size_t)tid * 16;
    char* d = dst + tid * 16;
    i32x4 r0 = ld16(a);
    i32x4 r1 = ld16(a + 6144);
    i32x4 r2 = {0, 0, 0, 0};
    bool gg = tid < 256;
    if (gg) r2 = ld16(a + 12288);
    vm_drain();
    *(i32x4*)d = r0;
    *(i32x4*)(d + 6144) = r1;
    if (gg) *(i32x4*)(d + 12288) = r2;
}

// ================= prep kernels (parallel, off critical path) =================

// GRU weights: [jf16(32)][kb(20: 0-15 Wh,16-19 Wi)][g(3)][hl(2)][64][8]
__global__ __launch_bounds__(256)
void pack_gru_w(const float* __restrict__ Wh, const float* __restrict__ Wi,
                u16* __restrict__ dst)
{
    int idx  = blockIdx.x * 256 + threadIdx.x;       // 32*20*3*64 = 122880
    int lane = idx & 63;
    int t    = idx >> 6;
    int g    = t % 3;  t /= 3;
    int kb   = t % 20; t /= 20;
    int jf16 = t;
    if (jf16 >= 32) return;
    int row = g * HID + jf16 * 16 + (lane & 15);
    int kk  = kb * 32 + (lane >> 4) * 8;
    float v[8];
    if (kb < 16) { const float* s = Wh + (size_t)row * HID + kk;
        #pragma unroll
        for (int i = 0; i < 8; ++i) v[i] = s[i];
    } else { const float* s = Wi + (size_t)row * ND + (kk - HID);
        #pragma unroll
        for (int i = 0; i < 8; ++i) v[i] = s[i];
    }
    size_t base = ((((size_t)(jf16 * 20 + kb) * 3 + g) * 2) * 64 + lane) * 8;
    #pragma unroll
    for (int i = 0; i < 8; ++i) {
        u16 hi = f2bf(v[i]);
        dst[base + i]       = hi;
        dst[base + 512 + i] = f2bf(v[i] - bf2f(hi));
    }
}

// Wc = dec_Wi @ Wo  [1536][256] -> frags [jf16(32)][kb(8)][g(3)][hl][64][8]
__global__ __launch_bounds__(256)
void pack_wc(const float* __restrict__ Wi, const float* __restrict__ Wo,
             u16* __restrict__ dst)
{
    int idx  = blockIdx.x * 256 + threadIdx.x;       // 32*8*3*64 = 49152
    int lane = idx & 63;
    int t    = idx >> 6;
    int g    = t % 3; t /= 3;
    int kb   = t % 8; t /= 8;
    int jf16 = t;
    if (jf16 >= 32) return;
    int row = g * HID + jf16 * 16 + (lane & 15);
    int p0  = kb * 32 + (lane >> 4) * 8;
    float acc[8] = {0.f,0.f,0.f,0.f,0.f,0.f,0.f,0.f};
    for (int o = 0; o < ND; ++o) {
        float wi = Wi[(size_t)row * ND + o];
        const float* wo = Wo + (size_t)o * PROJD + p0;
        #pragma unroll
        for (int i = 0; i < 8; ++i) acc[i] += wi * wo[i];
    }
    size_t base = ((((size_t)(jf16 * 8 + kb) * 3 + g) * 2) * 64 + lane) * 8;
    #pragma unroll
    for (int i = 0; i < 8; ++i) {
        u16 hi = f2bf(acc[i]);
        dst[base + i]       = hi;
        dst[base + 512 + i] = f2bf(acc[i] - bf2f(hi));
    }
}

// plain weight (no gates): [jf16][kb][hl][64][8]
__global__ __launch_bounds__(256)
void pack_plain_w(const float* __restrict__ W, int K, int NF, int KB,
                  u16* __restrict__ dst)
{
    int idx  = blockIdx.x * 256 + threadIdx.x;
    int lane = idx & 63;
    int t    = idx >> 6;
    int kb   = t % KB;
    int jf16 = t / KB;
    if (jf16 >= NF) return;
    int row = jf16 * 16 + (lane & 15);
    int kk  = kb * 32 + (lane >> 4) * 8;
    const float* s = W + (size_t)row * K + kk;
    size_t base = (((size_t)(jf16 * KB + kb) * 2) * 64 + lane) * 8;
    #pragma unroll
    for (int i = 0; i < 8; ++i) {
        float v = s[i];
        u16 hi = f2bf(v);
        dst[base + i]       = hi;
        dst[base + 512 + i] = f2bf(v - bf2f(hi));
    }
}

// X -> A-frags for every encoder step: [t(128)][bt(16)][kb(4)][hl][64][8]
__global__ __launch_bounds__(256)
void pack_xa(const float* __restrict__ X, u16* __restrict__ dst)
{
    int idx  = blockIdx.x * 256 + threadIdx.x;       // 128*16*4*64 = 524288
    int lane = idx & 63;
    int t2   = idx >> 6;
    int kb   = t2 & 3;  t2 >>= 2;
    int bt   = t2 & 15; t2 >>= 4;
    int t    = t2;
    if (t >= TIN) return;
    int b = bt * 16 + (lane & 15);
    int d = kb * 32 + (lane >> 4) * 8;
    const float* s = X + (size_t)b * TIN * ND + (size_t)t * ND + d;
    size_t base = ((((size_t)(t * 16 + bt) * 4 + kb) * 2) * 64 + lane) * 8;
    #pragma unroll
    for (int i = 0; i < 8; ++i) {
        float v = s[i];
        u16 hi = f2bf(v);
        dst[base + i]       = hi;
        dst[base + 512 + i] = f2bf(v - bf2f(hi));
    }
}

__global__ __launch_bounds__(256)
void prep_bias(const float* __restrict__ bi, const float* __restrict__ bh,
               float4* __restrict__ dst)
{
    int j = blockIdx.x * 256 + threadIdx.x;
    if (j >= HID) return;
    dst[j] = make_float4(bi[j] + bh[j],
                         bi[HID + j] + bh[HID + j],
                         bi[2 * HID + j],
                         bh[2 * HID + j]);
}

// decoder steps>=1: x-bias folded with Wi@bo
__global__ __launch_bounds__(256)
void prep_bias2(const float* __restrict__ bi, const float* __restrict__ bh,
                const float* __restrict__ Wi, const float* __restrict__ bo,
                float4* __restrict__ dst)
{
    int j = blockIdx.x * 256 + threadIdx.x;
    if (j >= HID) return;
    float w[3];
    #pragma unroll
    for (int g = 0; g < 3; ++g) {
        float s = 0.f;
        const float* wr = Wi + (size_t)(g * HID + j) * ND;
        for (int o = 0; o < ND; ++o) s += wr[o] * bo[o];
        w[g] = s;
    }
    dst[j] = make_float4(bi[j] + bh[j] + w[0],
                         bi[HID + j] + bh[HID + j] + w[1],
                         bi[2 * HID + j] + w[2],
                         bh[2 * HID + j]);
}

__global__ __launch_bounds__(256)
void zero_u32(unsigned int* __restrict__ p, int n) {
    int i = blockIdx.x * 256 + threadIdx.x;
    if (i < n) p[i] = 0u;
}

// ================= persistent cooperative kernel =============================
// grid 256 = (bt = bid&15, jq = bid>>4); 384 thr = 6 waves: (g = wv>>1, jh = wv&1)
// htag[bt*16+jq] at syncb + (bt*16+jq)*64B : value = # h publishes by that WG
// ptag[bt*8+jq]  at syncb + 16KB + (bt*8+jq)*64B : value = # proj publishes
__global__ __launch_bounds__(384, 1)
void seq_coop(const u16* __restrict__ encB, const u16* __restrict__ decB,
              const u16* __restrict__ WcB,  const u16* __restrict__ WpB,
              const u16* __restrict__ WoB,  const u16* __restrict__ xAe,
              u16* __restrict__ hA0, u16* __restrict__ hA1,
              u16* __restrict__ projA,
              const float4* __restrict__ biasE, const float4* __restrict__ biasD0,
              const float4* __restrict__ biasD1,
              const float* __restrict__ bp, const float* __restrict__ bo,
              float* __restrict__ d_out,
              unsigned int* __restrict__ syncb)
{
    const int tid  = threadIdx.x;
    const int lane = tid & 63;
    const int wv   = tid >> 6;
    const int bid  = blockIdx.x;
    const int bt   = bid & 15;
    const int jq   = bid >> 4;
    const int g    = wv >> 1;
    const int jh   = wv & 1;
    const int jf16 = jq * 2 + jh;

    unsigned int* htag = syncb + (size_t)bt * 16 * TAGSTRIDE;          // 16 tags
    unsigned int* ptag = syncb + 4096 + (size_t)bt * 8 * TAGSTRIDE;    // 8 tags
    unsigned int* htag_me = htag + (size_t)jq * TAGSTRIDE;
    unsigned int* ptag_me = ptag + (size_t)jq * TAGSTRIDE;             // jq<8 only

    __shared__ __align__(16) u16 hstage[16384];   // 32 KB: hA[bt] for this step
    __shared__ __align__(16) u16 pstage[8192];    // 16 KB: projA (x-part)
    __shared__ __align__(16) u16 ostage[8192];    // 16 KB: projA (out-phase)
    __shared__ float gx[4][16][36];               // gate exchange r,z,nh,nx
    __shared__ float hprev[16][36];               // persistent h (this WG's 32 cols)

    for (int e = tid; e < 16 * 36; e += 384) (&hprev[0][0])[e] = 0.f;

    // persistent h-part weights: 16 kb x {hi,lo}
    s16x8 wH0[16], wH1[16];
    #pragma unroll
    for (int kb = 0; kb < 16; ++kb) {
        size_t b0 = ((((size_t)jf16 * 20 + kb) * 3 + g) * 2) * 512 + (size_t)lane * 8;
        wH0[kb] = *(const s16x8*)(encB + b0);
        wH1[kb] = *(const s16x8*)(encB + b0 + 512);
    }

    for (int s = 0; s < 192; ++s) {
        if (s == 128) {
            #pragma unroll
            for (int kb = 0; kb < 16; ++kb) {
                size_t b0 = ((((size_t)jf16 * 20 + kb) * 3 + g) * 2) * 512 + (size_t)lane * 8;
                wH0[kb] = *(const s16x8*)(decB + b0);
                wH1[kb] = *(const s16x8*)(decB + b0 + 512);
            }
        }
        const u16* hin  = (s & 1) ? hA1 : hA0;
        u16*       hout = (s & 1) ? hA0 : hA1;

        // hoist encoder x-frag loads (independent of h) so they fly during the wait
        s16x8 xh[4], xl[4];
        if (s <= 128) {
            int t = (s < 128) ? s : (TIN - 1);
            const u16* xa = xAe + (size_t)(t * 16 + bt) * 4096;
            #pragma unroll
            for (int kb = 0; kb < 4; ++kb) {
                xh[kb] = *(const s16x8*)(xa + (size_t)kb * 1024 + lane * 8);
                xl[kb] = *(const s16x8*)(xa + (size_t)kb * 1024 + 512 + lane * 8);
            }
        }

        // ---- wait for h(s): wave1 polls the 16 producer tags, rest wait at bar ----
        if (s > 0) {
            if (wv == 1) poll_tags(htag, 16, (unsigned)s, lane);
            __syncthreads();
        }
        stage32k((const char*)hin + (size_t)bt * 32768, (char*)hstage, tid);
        __syncthreads();

        f32x4 a0 = fz(), a1 = fz(), a2 = fz();
        f32x4 x0 = fz(), x1 = fz(), x2 = fz();

        // ---- h part: K 0..511 from LDS, weights from VGPR ----
        #pragma unroll
        for (int kb = 0; kb < 16; ++kb) {
            s16x8 ahi = *(const s16x8*)&hstage[(size_t)kb * 1024 + lane * 8];
            s16x8 alo = *(const s16x8*)&hstage[(size_t)kb * 1024 + 512 + lane * 8];
            a0 = mfma16(ahi, wH0[kb], a0);
            a1 = mfma16(ahi, wH1[kb], a1);
            a2 = mfma16(alo, wH0[kb], a2);
        }

        // ---- x part ----
        if (s <= 128) {
            const u16* wsrc = (s < 128) ? encB : decB;
            #pragma unroll
            for (int kb = 0; kb < 4; ++kb) {
                size_t wb = ((((size_t)jf16 * 20 + 16 + kb) * 3 + g) * 2) * 512 + (size_t)lane * 8;
                s16x8 bhi = *(const s16x8*)(wsrc + wb);
                s16x8 blo = *(const s16x8*)(wsrc + wb + 512);
                if (g == 2) { x0 = mfma16(xh[kb], bhi, x0); x1 = mfma16(xh[kb], blo, x1); x2 = mfma16(xl[kb], bhi, x2); }
                else        { a0 = mfma16(xh[kb], bhi, a0); a1 = mfma16(xh[kb], blo, a1); a2 = mfma16(xl[kb], bhi, a2); }
            }
        } else {
            int t = s - 128;
            if (wv == 1) poll_tags(ptag, 8, (unsigned)t, lane);   // proj(t-1) ready
            __syncthreads();
            stage16k((const char*)projA + (size_t)((s - 129) & 1) * 262144
                     + (size_t)bt * 16384, (char*)pstage, tid);
            __syncthreads();
            #pragma unroll
            for (int kb = 0; kb < 8; ++kb) {
                s16x8 ahi = *(const s16x8*)&pstage[(size_t)kb * 1024 + lane * 8];
                s16x8 alo = *(const s16x8*)&pstage[(size_t)kb * 1024 + 512 + lane * 8];
                size_t wb = ((((size_t)jf16 * 8 + kb) * 3 + g) * 2) * 512 + (size_t)lane * 8;
                s16x8 bhi = *(const s16x8*)(WcB + wb);
                s16x8 blo = *(const s16x8*)(WcB + wb + 512);
                if (g == 2) { x0 = mfma16(ahi, bhi, x0); x1 = mfma16(ahi, blo, x1); x2 = mfma16(alo, bhi, x2); }
                else        { a0 = mfma16(ahi, bhi, a0); a1 = mfma16(ahi, blo, a1); a2 = mfma16(alo, bhi, a2); }
            }
        }

        f32x4 am = a0 + a1 + a2;
        f32x4 xm = x0 + x1 + x2;

        #pragma unroll
        for (int i = 0; i < 4; ++i) {
            int r  = (lane >> 4) * 4 + i;
            int lc = jh * 16 + (lane & 15);
            gx[g][r][lc] = am[i];
            if (g == 2) gx[3][r][lc] = xm[i];
        }
        __syncthreads();

        // ---- gates + h update (512 elems over 384 threads) ----
        {
            const float4* b4p = (s < 128) ? biasE : ((s == 128) ? biasD0 : biasD1);
            for (int e = tid; e < 512; e += 384) {
                int r = e >> 5, lc = e & 31;
                float4 b4 = b4p[jq * 32 + lc];
                float rg = 1.f / (1.f + __expf(-(gx[0][r][lc] + b4.x)));
                float zg = 1.f / (1.f + __expf(-(gx[1][r][lc] + b4.y)));
                float narg = gx[3][r][lc] + b4.z + rg * (gx[2][r][lc] + b4.w);
                float e2 = __expf(2.f * narg);
                float ng = 1.f - 2.f / (e2 + 1.f);
                float hv = (1.f - zg) * ng + zg * hprev[r][lc];
                hprev[r][lc] = hv;
                gx[0][r][lc] = hv;
            }
        }
        __syncthreads();

        // wave0: emit this WG's 32 h-cols as frag chunk jq; parallel tag publish
        if (wv == 0) {
            s16x8 vh, vl;
            #pragma unroll
            for (int i = 0; i < 8; ++i) {
                float v = gx[0][lane & 15][(lane >> 4) * 8 + i];
                u16 hi = f2bf(v);
                vh[i] = (short)hi;
                vl[i] = (short)f2bf(v - bf2f(hi));
            }
            char* dh = (char*)hout + (size_t)(bt * 16 + jq) * 2048 + (size_t)lane * 16;
            st16(dh,        __builtin_bit_cast(i32x4, vh));
            st16(dh + 1024, __builtin_bit_cast(i32x4, vl));
            vm_drain();                                 // data visible at LLC
            if (lane == 0) tag_store(htag_me, (unsigned)(s + 1));
        }
        // no barrier here: next loop's (wv==1) poll + barrier joins wave0

        // ---- decoder: proj phase (jq<8) / out phase (jq>=8) ----
        if (s >= 128) {
            int t = s - 128, par = t & 1;
            if (jq < 8) {
                if (wv == 1) poll_tags(htag, 16, (unsigned)(s + 1), lane);
                __syncthreads();
                stage32k((const char*)hout + (size_t)bt * 32768, (char*)hstage, tid);
                __syncthreads();
                if (wv < 2) {
                    int pf16 = jq * 2 + wv;
                    f32x4 p0 = fz(), p1 = fz(), p2 = fz();
                    const u16* wb = WpB + (size_t)pf16 * 16384;
                    #pragma unroll
                    for (int kb = 0; kb < 16; ++kb) {
                        s16x8 ahi = *(const s16x8*)&hstage[(size_t)kb * 1024 + lane * 8];
                        s16x8 alo = *(const s16x8*)&hstage[(size_t)kb * 1024 + 512 + lane * 8];
                        s16x8 bhi = *(const s16x8*)(wb + (size_t)kb * 1024 + lane * 8);
                        s16x8 blo = *(const s16x8*)(wb + (size_t)kb * 1024 + 512 + lane * 8);
                        p0 = mfma16(ahi, bhi, p0);
                        p1 = mfma16(ahi, blo, p1);
                        p2 = mfma16(alo, bhi, p2);
                    }
                    f32x4 pm = p0 + p1 + p2;
                    float bpv = bp[pf16 * 16 + (lane & 15)];
                    #pragma unroll
                    for (int i = 0; i < 4; ++i)
                        gx[0][(lane >> 4) * 4 + i][wv * 16 + (lane & 15)] = fmaxf(pm[i] + bpv, 0.f);
                }
                __syncthreads();
                if (wv == 2) {
                    s16x8 vh, vl;
                    #pragma unroll
                    for (int i = 0; i < 8; ++i) {
                        float v = gx[0][lane & 15][(lane >> 4) * 8 + i];
                        u16 hi = f2bf(v);
                        vh[i] = (short)hi;
                        vl[i] = (short)f2bf(v - bf2f(hi));
                    }
                    char* dp = (char*)projA + (size_t)par * 262144 + (size_t)bt * 16384
                             + (size_t)jq * 2048 + (size_t)lane * 16;
                    st16(dp,        __builtin_bit_cast(i32x4, vh));
                    st16(dp + 1024, __builtin_bit_cast(i32x4, vl));
                    vm_drain();
                    if (lane == 0) tag_store(ptag_me, (unsigned)(t + 1));
                }
                // no barrier: next iteration's poll+barrier joins
            } else if (t >= 1) {
                if (wv == 1) poll_tags(ptag, 8, (unsigned)t, lane);  // proj(t-1)
                __syncthreads();
                stage16k((const char*)projA + (size_t)((t - 1) & 1) * 262144
                         + (size_t)bt * 16384, (char*)ostage, tid);
                __syncthreads();
                if (wv == 0) {
                    int of16 = jq - 8;
                    f32x4 q0 = fz(), q1 = fz(), q2 = fz();
                    const u16* wb = WoB + (size_t)of16 * 8192;
                    #pragma unroll
                    for (int kb = 0; kb < 8; ++kb) {
                        s16x8 ahi = *(const s16x8*)&ostage[(size_t)kb * 1024 + lane * 8];
                        s16x8 alo = *(const s16x8*)&ostage[(size_t)kb * 1024 + 512 + lane * 8];
                        s16x8 bhi = *(const s16x8*)(wb + (size_t)kb * 1024 + lane * 8);
                        s16x8 blo = *(const s16x8*)(wb + (size_t)kb * 1024 + 512 + lane * 8);
                        q0 = mfma16(ahi, bhi, q0);
                        q1 = mfma16(ahi, blo, q1);
                        q2 = mfma16(alo, bhi, q2);
                    }
                    f32x4 qm = q0 + q1 + q2;
                    float bov = bo[of16 * 16 + (lane & 15)];
                    #pragma unroll
                    for (int i = 0; i < 4; ++i) {
                        int b = bt * 16 + (lane >> 4) * 4 + i;
                        d_out[(size_t)b * (TOUT * ND) + (size_t)(t - 1) * ND + of16 * 16 + (lane & 15)] = qm[i] + bov;
                    }
                }
            }
        }
    }

    // tail: out[63] reads proj(63) (parity 1)
    if (jq >= 8) {
        if (wv == 1) poll_tags(ptag, 8, (unsigned)TOUT, lane);
        __syncthreads();
        stage16k((const char*)projA + (size_t)262144 + (size_t)bt * 16384,
                 (char*)ostage, tid);
        __syncthreads();
        if (wv == 0) {
            int of16 = jq - 8;
            f32x4 q0 = fz(), q1 = fz(), q2 = fz();
            const u16* wb = WoB + (size_t)of16 * 8192;
            #pragma unroll
            for (int kb = 0; kb < 8; ++kb) {
                s16x8 ahi = *(const s16x8*)&ostage[(size_t)kb * 1024 + lane * 8];
                s16x8 alo = *(const s16x8*)&ostage[(size_t)kb * 1024 + 512 + lane * 8];
                s16x8 bhi = *(const s16x8*)(wb + (size_t)kb * 1024 + lane * 8);
                s16x8 blo = *(const s16x8*)(wb + (size_t)kb * 1024 + 512 + lane * 8);
                q0 = mfma16(ahi, bhi, q0);
                q1 = mfma16(ahi, blo, q1);
                q2 = mfma16(alo, bhi, q2);
            }
            f32x4 qm = q0 + q1 + q2;
            float bov = bo[of16 * 16 + (lane & 15)];
            #pragma unroll
            for (int i = 0; i < 4; ++i) {
                int b = bt * 16 + (lane >> 4) * 4 + i;
                d_out[(size_t)b * (TOUT * ND) + (size_t)63 * ND + of16 * 16 + (lane & 15)] = qm[i] + bov;
            }
        }
    }
}

// ================= host =================
extern "C" void kernel_launch(void* const* d_in, const int* in_sizes, int n_in,
                              void* d_out, int out_size, void* d_ws, size_t ws_size,
                              hipStream_t stream)
{
    (void)in_sizes; (void)n_in; (void)out_size; (void)ws_size;

    const float* X      = (const float*)d_in[0];
    const float* enc_Wi = (const float*)d_in[1];
    const float* enc_Wh = (const float*)d_in[2];
    const float* enc_bi = (const float*)d_in[3];
    const float* enc_bh = (const float*)d_in[4];
    const float* dec_Wi = (const float*)d_in[5];
    const float* dec_Wh = (const float*)d_in[6];
    const float* dec_bi = (const float*)d_in[7];
    const float* dec_bh = (const float*)d_in[8];
    const float* Wp     = (const float*)d_in[9];
    const float* bp     = (const float*)d_in[10];
    const float* Wo     = (const float*)d_in[11];
    const float* bo     = (const float*)d_in[12];
    float* outp = (float*)d_out;

    char* w = (char*)d_ws;
    size_t off = 0;
    auto alloc = [&](size_t bytes) { void* p = w + off; off += (bytes + 255) & ~(size_t)255; return p; };

    u16* encB  = (u16*)alloc((size_t)32 * 20 * 3 * 2 * 512 * 2);   // 3.93 MB
    u16* decB  = (u16*)alloc((size_t)32 * 20 * 3 * 2 * 512 * 2);   // 3.93 MB
    u16* WcB   = (u16*)alloc((size_t)32 * 8 * 3 * 2 * 512 * 2);    // 1.57 MB
    u16* WpB   = (u16*)alloc((size_t)16 * 16 * 2 * 512 * 2);       // 0.5 MB
    u16* WoB   = (u16*)alloc((size_t)8 * 8 * 2 * 512 * 2);         // 128 KB
    u16* xAe   = (u16*)alloc((size_t)TIN * 16 * 4 * 2 * 512 * 2);  // 16.8 MB
    u16* hA0   = (u16*)alloc((size_t)16 * 16 * 2 * 512 * 2);       // 512 KB
    u16* hA1   = (u16*)alloc((size_t)16 * 16 * 2 * 512 * 2);
    u16* projA = (u16*)alloc((size_t)2 * 16 * 8 * 2 * 512 * 2);    // 512 KB
    float4* biasE  = (float4*)alloc(HID * 16);
    float4* biasD0 = (float4*)alloc(HID * 16);
    float4* biasD1 = (float4*)alloc(HID * 16);
    unsigned int* syncb = (unsigned int*)alloc(24 * 1024);         // htag 16K + ptag 8K

    // prep (parallel, every call — deterministic)
    zero_u32<<<24, 256, 0, stream>>>(syncb, 6144);
    zero_u32<<<512, 256, 0, stream>>>((unsigned int*)hA0, 16 * 16 * 2 * 512 / 2);
    pack_gru_w<<<480, 256, 0, stream>>>(enc_Wh, enc_Wi, encB);
    pack_gru_w<<<480, 256, 0, stream>>>(dec_Wh, dec_Wi, decB);
    pack_wc<<<192, 256, 0, stream>>>(dec_Wi, Wo, WcB);
    pack_plain_w<<<64, 256, 0, stream>>>(Wp, HID, 16, 16, WpB);
    pack_plain_w<<<16, 256, 0, stream>>>(Wo, PROJD, 8, 8, WoB);
    pack_xa<<<2048, 256, 0, stream>>>(X, xAe);
    prep_bias<<<2, 256, 0, stream>>>(enc_bi, enc_bh, biasE);
    prep_bias<<<2, 256, 0, stream>>>(dec_bi, dec_bh, biasD0);
    prep_bias2<<<2, 256, 0, stream>>>(dec_bi, dec_bh, dec_Wi, bo, biasD1);

    void* args[] = { &encB, &decB, &WcB, &WpB, &WoB, &xAe, &hA0, &hA1, &projA,
                     &biasE, &biasD0, &biasD1, (void*)&bp, (void*)&bo, &outp,
                     &syncb };
    hipLaunchCooperativeKernel((void*)seq_coop, dim3(NWG), dim3(384), args, 0, stream);
}

// Round 10
// 1370.886 us; speedup vs baseline: 4.6197x; 1.1549x over previous
//
#include <hip/hip_runtime.h>
#include <math.h>

#define TIN   128
#define TOUT  64
#define ND    128
#define HID   512
#define PROJD 256
#define BSZ   256
#define NWG   256

using f32x4 = __attribute__((ext_vector_type(4))) float;
using s16x8 = __attribute__((ext_vector_type(8))) short;
using i32x4 = __attribute__((ext_vector_type(4))) int;
typedef unsigned short u16;

__device__ __forceinline__ u16 f2bf(float x) {
    unsigned int u = __builtin_bit_cast(unsigned int, x);
    u += 0x7fffu + ((u >> 16) & 1u);          // RNE (finite values)
    return (u16)(u >> 16);
}
__device__ __forceinline__ float bf2f(u16 b) {
    unsigned int u = ((unsigned int)b) << 16;
    return __builtin_bit_cast(float, u);
}
__device__ __forceinline__ f32x4 mfma16(s16x8 a, s16x8 b, f32x4 c) {
    return __builtin_amdgcn_mfma_f32_16x16x32_bf16(a, b, c, 0, 0, 0);
}
__device__ __forceinline__ f32x4 fz() { return (f32x4){0.f, 0.f, 0.f, 0.f}; }

// ---- batched LLC-coherent (L1/L2-bypass) data movement (round-7 proven) ----
__device__ __forceinline__ i32x4 ld16(const void* p) {
    i32x4 r;
    asm volatile("global_load_dwordx4 %0, %1, off sc0 sc1" : "=v"(r) : "v"(p) : "memory");
    return r;
}
__device__ __forceinline__ void st16(void* p, i32x4 v) {
    asm volatile("global_store_dwordx4 %0, %1, off sc0 sc1" :: "v"(p), "v"(v) : "memory");
}
__device__ __forceinline__ void vm_drain() {
    asm volatile("s_waitcnt vmcnt(0)" ::: "memory");
    __builtin_amdgcn_sched_barrier(0);
}

// ---- tag-based handoff: one 64B line per producer ----
// NEW: tags are sc0 sc1 BOTH sides (write-through to MALL / read from MALL),
// so observation latency is one MALL RTT instead of riding L2 evictions.
#define TAGSTRIDE 16   // u32 units = 64 B
__device__ __forceinline__ unsigned int tag_load(const unsigned int* p) {
    unsigned int v;
    asm volatile("global_load_dword %0, %1, off sc0 sc1\n\ts_waitcnt vmcnt(0)"
                 : "=v"(v) : "v"(p) : "memory");
    return v;
}
__device__ __forceinline__ void tag_store(unsigned int* p, unsigned int v) {
    asm volatile("global_store_dword %0, %1, off sc0 sc1" :: "v"(p), "v"(v) : "memory");
}
// wave-level: lanes 0..n-1 each poll a distinct tag line until >= tgt
__device__ __forceinline__ void poll_tags(const unsigned int* base, int n,
                                          unsigned int tgt, int lane) {
    const unsigned int* p = base + (size_t)(lane < n ? lane : 0) * TAGSTRIDE;
    while (tag_load(p) < tgt) __builtin_amdgcn_s_sleep(1);
}

// stage 32 KB global -> LDS, 384 threads, one vmcnt drain
__device__ __forceinline__ void stage32k(const char* src, char* dst, int tid) {
    const char* a = src + (size_t)tid * 16;
    char* d = dst + tid * 16;
    i32x4 r0 = ld16(a);
    i32x4 r1 = ld16(a + 6144);
    i32x4 r2 = ld16(a + 12288);
    i32x4 r3 = ld16(a + 18432);
    i32x4 r4 = ld16(a + 24576);
    i32x4 r5 = {0, 0, 0, 0};
    bool gg = tid < 128;
    if (gg) r5 = ld16(a + 30720);
    vm_drain();
    *(i32x4*)d = r0;
    *(i32x4*)(d + 6144) = r1;
    *(i32x4*)(d + 12288) = r2;
    *(i32x4*)(d + 18432) = r3;
    *(i32x4*)(d + 24576) = r4;
    if (gg) *(i32x4*)(d + 30720) = r5;
}
// stage 16 KB global -> LDS
__device__ __forceinline__ void stage16k(const char* src, char* dst, int tid) {
    const char* a = src + (size_t)tid * 16;
    char* d = dst + tid * 16;
    i32x4 r0 = ld16(a);
    i32x4 r1 = ld16(a + 6144);
    i32x4 r2 = {0, 0, 0, 0};
    bool gg = tid < 256;
    if (gg) r2 = ld16(a + 12288);
    vm_drain();
    *(i32x4*)d = r0;
    *(i32x4*)(d + 6144) = r1;
    if (gg) *(i32x4*)(d + 12288) = r2;
}

// ================= prep kernels (parallel, off critical path) =================

// GRU weights: [jf16(32)][kb(20: 0-15 Wh,16-19 Wi)][g(3)][hl(2)][64][8]
__global__ __launch_bounds__(256)
void pack_gru_w(const float* __restrict__ Wh, const float* __restrict__ Wi,
                u16* __restrict__ dst)
{
    int idx  = blockIdx.x * 256 + threadIdx.x;       // 32*20*3*64 = 122880
    int lane = idx & 63;
    int t    = idx >> 6;
    int g    = t % 3;  t /= 3;
    int kb   = t % 20; t /= 20;
    int jf16 = t;
    if (jf16 >= 32) return;
    int row = g * HID + jf16 * 16 + (lane & 15);
    int kk  = kb * 32 + (lane >> 4) * 8;
    float v[8];
    if (kb < 16) { const float* s = Wh + (size_t)row * HID + kk;
        #pragma unroll
        for (int i = 0; i < 8; ++i) v[i] = s[i];
    } else { const float* s = Wi + (size_t)row * ND + (kk - HID);
        #pragma unroll
        for (int i = 0; i < 8; ++i) v[i] = s[i];
    }
    size_t base = ((((size_t)(jf16 * 20 + kb) * 3 + g) * 2) * 64 + lane) * 8;
    #pragma unroll
    for (int i = 0; i < 8; ++i) {
        u16 hi = f2bf(v[i]);
        dst[base + i]       = hi;
        dst[base + 512 + i] = f2bf(v[i] - bf2f(hi));
    }
}

// Wc = dec_Wi @ Wo  [1536][256] -> frags [jf16(32)][kb(8)][g(3)][hl][64][8]
__global__ __launch_bounds__(256)
void pack_wc(const float* __restrict__ Wi, const float* __restrict__ Wo,
             u16* __restrict__ dst)
{
    int idx  = blockIdx.x * 256 + threadIdx.x;       // 32*8*3*64 = 49152
    int lane = idx & 63;
    int t    = idx >> 6;
    int g    = t % 3; t /= 3;
    int kb   = t % 8; t /= 8;
    int jf16 = t;
    if (jf16 >= 32) return;
    int row = g * HID + jf16 * 16 + (lane & 15);
    int p0  = kb * 32 + (lane >> 4) * 8;
    float acc[8] = {0.f,0.f,0.f,0.f,0.f,0.f,0.f,0.f};
    for (int o = 0; o < ND; ++o) {
        float wi = Wi[(size_t)row * ND + o];
        const float* wo = Wo + (size_t)o * PROJD + p0;
        #pragma unroll
        for (int i = 0; i < 8; ++i) acc[i] += wi * wo[i];
    }
    size_t base = ((((size_t)(jf16 * 8 + kb) * 3 + g) * 2) * 64 + lane) * 8;
    #pragma unroll
    for (int i = 0; i < 8; ++i) {
        u16 hi = f2bf(acc[i]);
        dst[base + i]       = hi;
        dst[base + 512 + i] = f2bf(acc[i] - bf2f(hi));
    }
}

// plain weight (no gates): [jf16][kb][hl][64][8]
__global__ __launch_bounds__(256)
void pack_plain_w(const float* __restrict__ W, int K, int NF, int KB,
                  u16* __restrict__ dst)
{
    int idx  = blockIdx.x * 256 + threadIdx.x;
    int lane = idx & 63;
    int t    = idx >> 6;
    int kb   = t % KB;
    int jf16 = t / KB;
    if (jf16 >= NF) return;
    int row = jf16 * 16 + (lane & 15);
    int kk  = kb * 32 + (lane >> 4) * 8;
    const float* s = W + (size_t)row * K + kk;
    size_t base = (((size_t)(jf16 * KB + kb) * 2) * 64 + lane) * 8;
    #pragma unroll
    for (int i = 0; i < 8; ++i) {
        float v = s[i];
        u16 hi = f2bf(v);
        dst[base + i]       = hi;
        dst[base + 512 + i] = f2bf(v - bf2f(hi));
    }
}

// X -> A-frags for every encoder step: [t(128)][bt(16)][kb(4)][hl][64][8]
__global__ __launch_bounds__(256)
void pack_xa(const float* __restrict__ X, u16* __restrict__ dst)
{
    int idx  = blockIdx.x * 256 + threadIdx.x;       // 128*16*4*64 = 524288
    int lane = idx & 63;
    int t2   = idx >> 6;
    int kb   = t2 & 3;  t2 >>= 2;
    int bt   = t2 & 15; t2 >>= 4;
    int t    = t2;
    if (t >= TIN) return;
    int b = bt * 16 + (lane & 15);
    int d = kb * 32 + (lane >> 4) * 8;
    const float* s = X + (size_t)b * TIN * ND + (size_t)t * ND + d;
    size_t base = ((((size_t)(t * 16 + bt) * 4 + kb) * 2) * 64 + lane) * 8;
    #pragma unroll
    for (int i = 0; i < 8; ++i) {
        float v = s[i];
        u16 hi = f2bf(v);
        dst[base + i]       = hi;
        dst[base + 512 + i] = f2bf(v - bf2f(hi));
    }
}

__global__ __launch_bounds__(256)
void prep_bias(const float* __restrict__ bi, const float* __restrict__ bh,
               float4* __restrict__ dst)
{
    int j = blockIdx.x * 256 + threadIdx.x;
    if (j >= HID) return;
    dst[j] = make_float4(bi[j] + bh[j],
                         bi[HID + j] + bh[HID + j],
                         bi[2 * HID + j],
                         bh[2 * HID + j]);
}

// decoder steps>=1: x-bias folded with Wi@bo
__global__ __launch_bounds__(256)
void prep_bias2(const float* __restrict__ bi, const float* __restrict__ bh,
                const float* __restrict__ Wi, const float* __restrict__ bo,
                float4* __restrict__ dst)
{
    int j = blockIdx.x * 256 + threadIdx.x;
    if (j >= HID) return;
    float w[3];
    #pragma unroll
    for (int g = 0; g < 3; ++g) {
        float s = 0.f;
        const float* wr = Wi + (size_t)(g * HID + j) * ND;
        for (int o = 0; o < ND; ++o) s += wr[o] * bo[o];
        w[g] = s;
    }
    dst[j] = make_float4(bi[j] + bh[j] + w[0],
                         bi[HID + j] + bh[HID + j] + w[1],
                         bi[2 * HID + j] + w[2],
                         bh[2 * HID + j]);
}

__global__ __launch_bounds__(256)
void zero_u32(unsigned int* __restrict__ p, int n) {
    int i = blockIdx.x * 256 + threadIdx.x;
    if (i < n) p[i] = 0u;
}

// ================= persistent cooperative kernel =============================
// grid 256 = (bt = bid&15, jq = bid>>4); 384 thr = 6 waves: (g = wv>>1, jh = wv&1)
// htag[bt*16+jq] : # h publishes by that WG.  ptag[bt*8+jq] : # proj publishes.
// Decoder optimization: the late phase at iter s stages h(s+1) into hstage for
// ALL WGs, so iteration s+1 (s+1>=129) skips its wait+stage entirely.
__global__ __launch_bounds__(384, 1)
void seq_coop(const u16* __restrict__ encB, const u16* __restrict__ decB,
              const u16* __restrict__ WcB,  const u16* __restrict__ WpB,
              const u16* __restrict__ WoB,  const u16* __restrict__ xAe,
              u16* __restrict__ hA0, u16* __restrict__ hA1,
              u16* __restrict__ projA,
              const float4* __restrict__ biasE, const float4* __restrict__ biasD0,
              const float4* __restrict__ biasD1,
              const float* __restrict__ bp, const float* __restrict__ bo,
              float* __restrict__ d_out,
              unsigned int* __restrict__ syncb)
{
    const int tid  = threadIdx.x;
    const int lane = tid & 63;
    const int wv   = tid >> 6;
    const int bid  = blockIdx.x;
    const int bt   = bid & 15;
    const int jq   = bid >> 4;
    const int g    = wv >> 1;
    const int jh   = wv & 1;
    const int jf16 = jq * 2 + jh;

    unsigned int* htag = syncb + (size_t)bt * 16 * TAGSTRIDE;          // 16 tags
    unsigned int* ptag = syncb + 4096 + (size_t)bt * 8 * TAGSTRIDE;    // 8 tags
    unsigned int* htag_me = htag + (size_t)jq * TAGSTRIDE;
    unsigned int* ptag_me = ptag + (size_t)jq * TAGSTRIDE;             // jq<8 only

    __shared__ __align__(16) u16 hstage[16384];   // 32 KB: hA[bt] for this step
    __shared__ __align__(16) u16 pstage[8192];    // 16 KB: projA (x-part)
    __shared__ __align__(16) u16 ostage[8192];    // 16 KB: projA (out-phase)
    __shared__ float gx[4][16][36];               // gate exchange r,z,nh,nx
    __shared__ float hprev[16][36];               // persistent h (this WG's 32 cols)

    for (int e = tid; e < 16 * 36; e += 384) (&hprev[0][0])[e] = 0.f;

    // persistent h-part weights: 16 kb x {hi,lo}
    s16x8 wH0[16], wH1[16];
    #pragma unroll
    for (int kb = 0; kb < 16; ++kb) {
        size_t b0 = ((((size_t)jf16 * 20 + kb) * 3 + g) * 2) * 512 + (size_t)lane * 8;
        wH0[kb] = *(const s16x8*)(encB + b0);
        wH1[kb] = *(const s16x8*)(encB + b0 + 512);
    }

    for (int s = 0; s < 192; ++s) {
        if (s == 128) {
            #pragma unroll
            for (int kb = 0; kb < 16; ++kb) {
                size_t b0 = ((((size_t)jf16 * 20 + kb) * 3 + g) * 2) * 512 + (size_t)lane * 8;
                wH0[kb] = *(const s16x8*)(decB + b0);
                wH1[kb] = *(const s16x8*)(decB + b0 + 512);
            }
        }
        const u16* hin  = (s & 1) ? hA1 : hA0;
        u16*       hout = (s & 1) ? hA0 : hA1;

        f32x4 a0 = fz(), a1 = fz(), a2 = fz();
        f32x4 x0 = fz(), x1 = fz(), x2 = fz();

        // ---- x part FIRST for s<=128 (independent of h: overlaps the wait) ----
        if (s <= 128) {
            int t = (s < 128) ? s : (TIN - 1);
            const u16* wsrc = (s < 128) ? encB : decB;
            const u16* xa = xAe + (size_t)(t * 16 + bt) * 4096;
            #pragma unroll
            for (int kb = 0; kb < 4; ++kb) {
                s16x8 ahi = *(const s16x8*)(xa + (size_t)kb * 1024 + lane * 8);
                s16x8 alo = *(const s16x8*)(xa + (size_t)kb * 1024 + 512 + lane * 8);
                size_t wb = ((((size_t)jf16 * 20 + 16 + kb) * 3 + g) * 2) * 512 + (size_t)lane * 8;
                s16x8 bhi = *(const s16x8*)(wsrc + wb);
                s16x8 blo = *(const s16x8*)(wsrc + wb + 512);
                if (g == 2) { x0 = mfma16(ahi, bhi, x0); x1 = mfma16(ahi, blo, x1); x2 = mfma16(alo, bhi, x2); }
                else        { a0 = mfma16(ahi, bhi, a0); a1 = mfma16(ahi, blo, a1); a2 = mfma16(alo, bhi, a2); }
            }
            // ---- wait for h(s) + stage (skipped for s>=129: prefilled) ----
            if (s > 0) {
                if (wv == 1) poll_tags(htag, 16, (unsigned)s, lane);
                __syncthreads();
            }
            stage32k((const char*)hin + (size_t)bt * 32768, (char*)hstage, tid);
            __syncthreads();
        }

        // ---- h part: K 0..511 from LDS (prefilled for s>=129), weights in VGPR ----
        #pragma unroll
        for (int kb = 0; kb < 16; ++kb) {
            s16x8 ahi = *(const s16x8*)&hstage[(size_t)kb * 1024 + lane * 8];
            s16x8 alo = *(const s16x8*)&hstage[(size_t)kb * 1024 + 512 + lane * 8];
            a0 = mfma16(ahi, wH0[kb], a0);
            a1 = mfma16(ahi, wH1[kb], a1);
            a2 = mfma16(alo, wH0[kb], a2);
        }

        // ---- decoder x part (s>=129): proj(t-1) frags via Wc ----
        if (s > 128) {
            int t = s - 128;
            if (wv == 1) poll_tags(ptag, 8, (unsigned)t, lane);   // proj(t-1) ready
            __syncthreads();
            stage16k((const char*)projA + (size_t)((s - 129) & 1) * 262144
                     + (size_t)bt * 16384, (char*)pstage, tid);
            __syncthreads();
            #pragma unroll
            for (int kb = 0; kb < 8; ++kb) {
                s16x8 ahi = *(const s16x8*)&pstage[(size_t)kb * 1024 + lane * 8];
                s16x8 alo = *(const s16x8*)&pstage[(size_t)kb * 1024 + 512 + lane * 8];
                size_t wb = ((((size_t)jf16 * 8 + kb) * 3 + g) * 2) * 512 + (size_t)lane * 8;
                s16x8 bhi = *(const s16x8*)(WcB + wb);
                s16x8 blo = *(const s16x8*)(WcB + wb + 512);
                if (g == 2) { x0 = mfma16(ahi, bhi, x0); x1 = mfma16(ahi, blo, x1); x2 = mfma16(alo, bhi, x2); }
                else        { a0 = mfma16(ahi, bhi, a0); a1 = mfma16(ahi, blo, a1); a2 = mfma16(alo, bhi, a2); }
            }
        }

        f32x4 am = a0 + a1 + a2;
        f32x4 xm = x0 + x1 + x2;

        #pragma unroll
        for (int i = 0; i < 4; ++i) {
            int r  = (lane >> 4) * 4 + i;
            int lc = jh * 16 + (lane & 15);
            gx[g][r][lc] = am[i];
            if (g == 2) gx[3][r][lc] = xm[i];
        }
        __syncthreads();

        // ---- gates + h update (512 elems over 384 threads) ----
        {
            const float4* b4p = (s < 128) ? biasE : ((s == 128) ? biasD0 : biasD1);
            for (int e = tid; e < 512; e += 384) {
                int r = e >> 5, lc = e & 31;
                float4 b4 = b4p[jq * 32 + lc];
                float rg = 1.f / (1.f + __expf(-(gx[0][r][lc] + b4.x)));
                float zg = 1.f / (1.f + __expf(-(gx[1][r][lc] + b4.y)));
                float narg = gx[3][r][lc] + b4.z + rg * (gx[2][r][lc] + b4.w);
                float e2 = __expf(2.f * narg);
                float ng = 1.f - 2.f / (e2 + 1.f);
                float hv = (1.f - zg) * ng + zg * hprev[r][lc];
                hprev[r][lc] = hv;
                gx[0][r][lc] = hv;
            }
        }
        __syncthreads();

        // wave0: emit this WG's 32 h-cols as frag chunk jq; tag publish
        if (wv == 0) {
            s16x8 vh, vl;
            #pragma unroll
            for (int i = 0; i < 8; ++i) {
                float v = gx[0][lane & 15][(lane >> 4) * 8 + i];
                u16 hi = f2bf(v);
                vh[i] = (short)hi;
                vl[i] = (short)f2bf(v - bf2f(hi));
            }
            char* dh = (char*)hout + (size_t)(bt * 16 + jq) * 2048 + (size_t)lane * 16;
            st16(dh,        __builtin_bit_cast(i32x4, vh));
            st16(dh + 1024, __builtin_bit_cast(i32x4, vl));
            vm_drain();                                 // data visible at MALL
            if (lane == 0) tag_store(htag_me, (unsigned)(s + 1));
        }
        // no barrier here: next phase's poll + barrier joins wave0

        // ---- decoder late phase: proj (jq<8) / out + h-prefetch (jq>=8) ----
        if (s >= 128) {
            int t = s - 128, par = t & 1;
            if (jq < 8) {
                if (wv == 1) poll_tags(htag, 16, (unsigned)(s + 1), lane);
                __syncthreads();
                stage32k((const char*)hout + (size_t)bt * 32768, (char*)hstage, tid);
                __syncthreads();
                if (wv < 2) {
                    int pf16 = jq * 2 + wv;
                    f32x4 p0 = fz(), p1 = fz(), p2 = fz();
                    const u16* wb = WpB + (size_t)pf16 * 16384;
                    #pragma unroll
                    for (int kb = 0; kb < 16; ++kb) {
                        s16x8 ahi = *(const s16x8*)&hstage[(size_t)kb * 1024 + lane * 8];
                        s16x8 alo = *(const s16x8*)&hstage[(size_t)kb * 1024 + 512 + lane * 8];
                        s16x8 bhi = *(const s16x8*)(wb + (size_t)kb * 1024 + lane * 8);
                        s16x8 blo = *(const s16x8*)(wb + (size_t)kb * 1024 + 512 + lane * 8);
                        p0 = mfma16(ahi, bhi, p0);
                        p1 = mfma16(ahi, blo, p1);
                        p2 = mfma16(alo, bhi, p2);
                    }
                    f32x4 pm = p0 + p1 + p2;
                    float bpv = bp[pf16 * 16 + (lane & 15)];
                    #pragma unroll
                    for (int i = 0; i < 4; ++i)
                        gx[0][(lane >> 4) * 4 + i][wv * 16 + (lane & 15)] = fmaxf(pm[i] + bpv, 0.f);
                }
                __syncthreads();
                if (wv == 2) {
                    s16x8 vh, vl;
                    #pragma unroll
                    for (int i = 0; i < 8; ++i) {
                        float v = gx[0][lane & 15][(lane >> 4) * 8 + i];
                        u16 hi = f2bf(v);
                        vh[i] = (short)hi;
                        vl[i] = (short)f2bf(v - bf2f(hi));
                    }
                    char* dp = (char*)projA + (size_t)par * 262144 + (size_t)bt * 16384
                             + (size_t)jq * 2048 + (size_t)lane * 16;
                    st16(dp,        __builtin_bit_cast(i32x4, vh));
                    st16(dp + 1024, __builtin_bit_cast(i32x4, vl));
                    vm_drain();
                    if (lane == 0) tag_store(ptag_me, (unsigned)(t + 1));
                }
            } else {
                if (wv == 1) {
                    poll_tags(htag, 16, (unsigned)(s + 1), lane);
                    if (t >= 1) poll_tags(ptag, 8, (unsigned)t, lane);
                }
                __syncthreads();
                stage32k((const char*)hout + (size_t)bt * 32768, (char*)hstage, tid);
                if (t >= 1)
                    stage16k((const char*)projA + (size_t)((t - 1) & 1) * 262144
                             + (size_t)bt * 16384, (char*)ostage, tid);
                __syncthreads();
                if (t >= 1 && wv == 0) {
                    int of16 = jq - 8;
                    f32x4 q0 = fz(), q1 = fz(), q2 = fz();
                    const u16* wb = WoB + (size_t)of16 * 8192;
                    #pragma unroll
                    for (int kb = 0; kb < 8; ++kb) {
                        s16x8 ahi = *(const s16x8*)&ostage[(size_t)kb * 1024 + lane * 8];
                        s16x8 alo = *(const s16x8*)&ostage[(size_t)kb * 1024 + 512 + lane * 8];
                        s16x8 bhi = *(const s16x8*)(wb + (size_t)kb * 1024 + lane * 8);
                        s16x8 blo = *(const s16x8*)(wb + (size_t)kb * 1024 + 512 + lane * 8);
                        q0 = mfma16(ahi, bhi, q0);
                        q1 = mfma16(ahi, blo, q1);
                        q2 = mfma16(alo, bhi, q2);
                    }
                    f32x4 qm = q0 + q1 + q2;
                    float bov = bo[of16 * 16 + (lane & 15)];
                    #pragma unroll
                    for (int i = 0; i < 4; ++i) {
                        int b = bt * 16 + (lane >> 4) * 4 + i;
                        d_out[(size_t)b * (TOUT * ND) + (size_t)(t - 1) * ND + of16 * 16 + (lane & 15)] = qm[i] + bov;
                    }
                }
            }
        }
    }

    // tail: out[63] reads proj(63) (parity 1)
    if (jq >= 8) {
        if (wv == 1) poll_tags(ptag, 8, (unsigned)TOUT, lane);
        __syncthreads();
        stage16k((const char*)projA + (size_t)262144 + (size_t)bt * 16384,
                 (char*)ostage, tid);
        __syncthreads();
        if (wv == 0) {
            int of16 = jq - 8;
            f32x4 q0 = fz(), q1 = fz(), q2 = fz();
            const u16* wb = WoB + (size_t)of16 * 8192;
            #pragma unroll
            for (int kb = 0; kb < 8; ++kb) {
                s16x8 ahi = *(const s16x8*)&ostage[(size_t)kb * 1024 + lane * 8];
                s16x8 alo = *(const s16x8*)&ostage[(size_t)kb * 1024 + 512 + lane * 8];
                s16x8 bhi = *(const s16x8*)(wb + (size_t)kb * 1024 + lane * 8);
                s16x8 blo = *(const s16x8*)(wb + (size_t)kb * 1024 + 512 + lane * 8);
                q0 = mfma16(ahi, bhi, q0);
                q1 = mfma16(ahi, blo, q1);
                q2 = mfma16(alo, bhi, q2);
            }
            f32x4 qm = q0 + q1 + q2;
            float bov = bo[of16 * 16 + (lane & 15)];
            #pragma unroll
            for (int i = 0; i < 4; ++i) {
                int b = bt * 16 + (lane >> 4) * 4 + i;
                d_out[(size_t)b * (TOUT * ND) + (size_t)63 * ND + of16 * 16 + (lane & 15)] = qm[i] + bov;
            }
        }
    }
}

// ================= host =================
extern "C" void kernel_launch(void* const* d_in, const int* in_sizes, int n_in,
                              void* d_out, int out_size, void* d_ws, size_t ws_size,
                              hipStream_t stream)
{
    (void)in_sizes; (void)n_in; (void)out_size; (void)ws_size;

    const float* X      = (const float*)d_in[0];
    const float* enc_Wi = (const float*)d_in[1];
    const float* enc_Wh = (const float*)d_in[2];
    const float* enc_bi = (const float*)d_in[3];
    const float* enc_bh = (const float*)d_in[4];
    const float* dec_Wi = (const float*)d_in[5];
    const float* dec_Wh = (const float*)d_in[6];
    const float* dec_bi = (const float*)d_in[7];
    const float* dec_bh = (const float*)d_in[8];
    const float* Wp     = (const float*)d_in[9];
    const float* bp     = (const float*)d_in[10];
    const float* Wo     = (const float*)d_in[11];
    const float* bo     = (const float*)d_in[12];
    float* outp = (float*)d_out;

    char* w = (char*)d_ws;
    size_t off = 0;
    auto alloc = [&](size_t bytes) { void* p = w + off; off += (bytes + 255) & ~(size_t)255; return p; };

    u16* encB  = (u16*)alloc((size_t)32 * 20 * 3 * 2 * 512 * 2);   // 3.93 MB
    u16* decB  = (u16*)alloc((size_t)32 * 20 * 3 * 2 * 512 * 2);   // 3.93 MB
    u16* WcB   = (u16*)alloc((size_t)32 * 8 * 3 * 2 * 512 * 2);    // 1.57 MB
    u16* WpB   = (u16*)alloc((size_t)16 * 16 * 2 * 512 * 2);       // 0.5 MB
    u16* WoB   = (u16*)alloc((size_t)8 * 8 * 2 * 512 * 2);         // 128 KB
    u16* xAe   = (u16*)alloc((size_t)TIN * 16 * 4 * 2 * 512 * 2);  // 16.8 MB
    u16* hA0   = (u16*)alloc((size_t)16 * 16 * 2 * 512 * 2);       // 512 KB
    u16* hA1   = (u16*)alloc((size_t)16 * 16 * 2 * 512 * 2);
    u16* projA = (u16*)alloc((size_t)2 * 16 * 8 * 2 * 512 * 2);    // 512 KB
    float4* biasE  = (float4*)alloc(HID * 16);
    float4* biasD0 = (float4*)alloc(HID * 16);
    float4* biasD1 = (float4*)alloc(HID * 16);
    unsigned int* syncb = (unsigned int*)alloc(24 * 1024);         // htag 16K + ptag 8K

    // prep (parallel, every call — deterministic)
    zero_u32<<<24, 256, 0, stream>>>(syncb, 6144);
    zero_u32<<<512, 256, 0, stream>>>((unsigned int*)hA0, 16 * 16 * 2 * 512 / 2);
    pack_gru_w<<<480, 256, 0, stream>>>(enc_Wh, enc_Wi, encB);
    pack_gru_w<<<480, 256, 0, stream>>>(dec_Wh, dec_Wi, decB);
    pack_wc<<<192, 256, 0, stream>>>(dec_Wi, Wo, WcB);
    pack_plain_w<<<64, 256, 0, stream>>>(Wp, HID, 16, 16, WpB);
    pack_plain_w<<<16, 256, 0, stream>>>(Wo, PROJD, 8, 8, WoB);
    pack_xa<<<2048, 256, 0, stream>>>(X, xAe);
    prep_bias<<<2, 256, 0, stream>>>(enc_bi, enc_bh, biasE);
    prep_bias<<<2, 256, 0, stream>>>(dec_bi, dec_bh, biasD0);
    prep_bias2<<<2, 256, 0, stream>>>(dec_bi, dec_bh, dec_Wi, bo, biasD1);

    void* args[] = { &encB, &decB, &WcB, &WpB, &WoB, &xAe, &hA0, &hA1, &projA,
                     &biasE, &biasD0, &biasD1, (void*)&bp, (void*)&bo, &outp,
                     &syncb };
    hipLaunchCooperativeKernel((void*)seq_coop, dim3(NWG), dim3(384), args, 0, stream);
}